// Round 4
// baseline (426.264 us; speedup 1.0000x reference)
//
#include <hip/hip_runtime.h>
#include <hip/hip_bf16.h>
#include <math.h>

#define NROWS 8192
#define DIN   512
#define DHID  256
#define DOUT  128
#define LOG2E 1.4426950408889634f

typedef unsigned short ushort_t;
typedef __attribute__((ext_vector_type(8))) short bf16x8;
typedef __attribute__((ext_vector_type(4))) float f32x4;

#if defined(__has_builtin)
#  if __has_builtin(__builtin_amdgcn_exp2f)
#    define FAST_EXP2(x) __builtin_amdgcn_exp2f(x)
#  else
#    define FAST_EXP2(x) exp2f(x)
#  endif
#else
#  define FAST_EXP2(x) exp2f(x)
#endif

__device__ __forceinline__ short f2bf(float x) {
  __hip_bfloat16 h = __float2bfloat16(x);
  return *(short*)&h;
}

__device__ __forceinline__ bf16x8 cvt8(float4 lo, float4 hi) {
  bf16x8 r;
  r[0] = f2bf(lo.x); r[1] = f2bf(lo.y); r[2] = f2bf(lo.z); r[3] = f2bf(lo.w);
  r[4] = f2bf(hi.x); r[5] = f2bf(hi.y); r[6] = f2bf(hi.z); r[7] = f2bf(hi.w);
  return r;
}

// ---------------------------------------------------------------------------
// Weight prep (all 3 heads): W1 (512x256)->w1t (256x512), W2 (256x128)->
// w2t (128x256), fp32 -> bf16, transposed so k is contiguous.
// grid (640, 3).
// ---------------------------------------------------------------------------
__global__ __launch_bounds__(256) void prep_w_kernel(
    const float* __restrict__ W1_0, const float* __restrict__ W1_1,
    const float* __restrict__ W1_2,
    const float* __restrict__ W2_0, const float* __restrict__ W2_1,
    const float* __restrict__ W2_2,
    ushort_t* __restrict__ w1t3, ushort_t* __restrict__ w2t3)
{
  const float* W1s[3] = {W1_0, W1_1, W1_2};
  const float* W2s[3] = {W2_0, W2_1, W2_2};
  const int z = blockIdx.y;
  int idx = blockIdx.x * 256 + threadIdx.x;
  if (idx < DHID * DIN) {
    int n = idx >> 9, k = idx & (DIN - 1);
    w1t3[(size_t)z * DHID * DIN + idx] = f2bf(W1s[z][(size_t)k * DHID + n]);
  } else {
    int j = idx - DHID * DIN;
    int n = j >> 8, k = j & (DHID - 1);
    w2t3[(size_t)z * DOUT * DHID + j] = f2bf(W2s[z][(size_t)k * DOUT + n]);
  }
}

// ---------------------------------------------------------------------------
// GEMM1 (all heads): H = relu(x @ W1 + b1). x fp32 loaded directly and
// converted in-register. Block 64x128 (waves 2x2, wave 32x64). K=512, 16 ki,
// ki-prefetched. grid (128, 2, 3).
// ---------------------------------------------------------------------------
__global__ __launch_bounds__(256) void gemm1_kernel(
    const float* __restrict__ x0, const float* __restrict__ x1,
    const float* __restrict__ x2,
    const ushort_t* __restrict__ w1t3,
    const float* __restrict__ b1_0, const float* __restrict__ b1_1,
    const float* __restrict__ b1_2,
    ushort_t* __restrict__ h3)
{
  const float* xs[3] = {x0, x1, x2};
  const float* bs[3] = {b1_0, b1_1, b1_2};
  const int z = blockIdx.z;
  const float* X = xs[z];
  const ushort_t* Bt = w1t3 + (size_t)z * DHID * DIN;
  ushort_t* H = h3 + (size_t)z * NROWS * DHID;

  const int tid = threadIdx.x, lane = tid & 63, wave = tid >> 6;
  const int wr = wave >> 1, wc = wave & 1, quad = lane >> 4, l16 = lane & 15;
  const int m0 = blockIdx.x * 64 + wr * 32;
  const int n0 = blockIdx.y * 128 + wc * 64;

  const float* px = X + (size_t)(m0 + l16) * DIN + quad * 8;
  const ushort_t* pb = Bt + (size_t)(n0 + l16) * DIN + quad * 8;

  f32x4 acc[2][4] = {};
  float4 af[2][2][2];
  bf16x8 b[2][4];
#pragma unroll
  for (int rt = 0; rt < 2; rt++) {
    af[0][rt][0] = *(const float4*)(px + rt * 16 * DIN);
    af[0][rt][1] = *(const float4*)(px + rt * 16 * DIN + 4);
  }
#pragma unroll
  for (int ct = 0; ct < 4; ct++) b[0][ct] = *(const bf16x8*)(pb + ct * 16 * DIN);

#pragma unroll
  for (int ki = 0; ki < 16; ki++) {
    const int cur = ki & 1;
    if (ki < 15) {
      const int off = (ki + 1) * 32;
#pragma unroll
      for (int rt = 0; rt < 2; rt++) {
        af[cur ^ 1][rt][0] = *(const float4*)(px + rt * 16 * DIN + off);
        af[cur ^ 1][rt][1] = *(const float4*)(px + rt * 16 * DIN + off + 4);
      }
#pragma unroll
      for (int ct = 0; ct < 4; ct++)
        b[cur ^ 1][ct] = *(const bf16x8*)(pb + ct * 16 * DIN + off);
    }
    bf16x8 a[2];
#pragma unroll
    for (int rt = 0; rt < 2; rt++) a[rt] = cvt8(af[cur][rt][0], af[cur][rt][1]);
#pragma unroll
    for (int rt = 0; rt < 2; rt++)
#pragma unroll
      for (int ct = 0; ct < 4; ct++)
        acc[rt][ct] = __builtin_amdgcn_mfma_f32_16x16x32_bf16(
            a[rt], b[cur][ct], acc[rt][ct], 0, 0, 0);
  }

  float bb[4];
#pragma unroll
  for (int ct = 0; ct < 4; ct++) bb[ct] = bs[z][n0 + ct * 16 + l16];
#pragma unroll
  for (int rt = 0; rt < 2; rt++)
#pragma unroll
    for (int ct = 0; ct < 4; ct++)
#pragma unroll
      for (int reg = 0; reg < 4; reg++) {
        float v = fmaxf(acc[rt][ct][reg] + bb[ct], 0.0f);
        H[(size_t)(m0 + rt * 16 + quad * 4 + reg) * DHID + n0 + ct * 16 + l16] =
            (ushort_t)f2bf(v);
      }
}

// ---------------------------------------------------------------------------
// GEMM2 (all heads): Y = H @ W2 + b2 (fp32) + column sum/sumsq atomics.
// Block 32x128 (waves 2x2, wave 16x64). K=256, 8 ki, prefetched.
// grid (256, 1, 3).
// ---------------------------------------------------------------------------
__global__ __launch_bounds__(256) void gemm2_kernel(
    const ushort_t* __restrict__ h3, const ushort_t* __restrict__ w2t3,
    const float* __restrict__ b2_0, const float* __restrict__ b2_1,
    const float* __restrict__ b2_2,
    float* __restrict__ y3,
    float* __restrict__ colsum, float* __restrict__ colsumsq)
{
  const float* bs[3] = {b2_0, b2_1, b2_2};
  const int z = blockIdx.z;
  const ushort_t* A = h3 + (size_t)z * NROWS * DHID;
  const ushort_t* Bt = w2t3 + (size_t)z * DOUT * DHID;
  float* Y = y3 + (size_t)z * NROWS * DOUT;
  float* csum = colsum + z * DOUT;
  float* csq  = colsumsq + z * DOUT;

  const int tid = threadIdx.x, lane = tid & 63, wave = tid >> 6;
  const int wr = wave >> 1, wc = wave & 1, quad = lane >> 4, l16 = lane & 15;
  const int m0 = blockIdx.x * 32 + wr * 16;
  const int n0 = wc * 64;

  const ushort_t* pa = A + (size_t)(m0 + l16) * DHID + quad * 8;
  const ushort_t* pb = Bt + (size_t)(n0 + l16) * DHID + quad * 8;

  f32x4 acc[4] = {};
  bf16x8 a[2], b[2][4];
  a[0] = *(const bf16x8*)pa;
#pragma unroll
  for (int ct = 0; ct < 4; ct++) b[0][ct] = *(const bf16x8*)(pb + ct * 16 * DHID);

#pragma unroll
  for (int ki = 0; ki < 8; ki++) {
    const int cur = ki & 1;
    if (ki < 7) {
      const int off = (ki + 1) * 32;
      a[cur ^ 1] = *(const bf16x8*)(pa + off);
#pragma unroll
      for (int ct = 0; ct < 4; ct++)
        b[cur ^ 1][ct] = *(const bf16x8*)(pb + ct * 16 * DHID + off);
    }
#pragma unroll
    for (int ct = 0; ct < 4; ct++)
      acc[ct] = __builtin_amdgcn_mfma_f32_16x16x32_bf16(
          a[cur], b[cur][ct], acc[ct], 0, 0, 0);
  }

  float bb[4];
#pragma unroll
  for (int ct = 0; ct < 4; ct++) bb[ct] = bs[z][n0 + ct * 16 + l16];
#pragma unroll
  for (int ct = 0; ct < 4; ct++) {
    float cs = 0.0f, cq = 0.0f;
#pragma unroll
    for (int reg = 0; reg < 4; reg++) {
      float v = acc[ct][reg] + bb[ct];
      Y[(size_t)(m0 + quad * 4 + reg) * DOUT + n0 + ct * 16 + l16] = v;
      cs += v; cq += v * v;
    }
    cs += __shfl_xor(cs, 16, 64); cs += __shfl_xor(cs, 32, 64);
    cq += __shfl_xor(cq, 16, 64); cq += __shfl_xor(cq, 32, 64);
    if (lane < 16) {
      atomicAdd(&csum[n0 + ct * 16 + l16], cs);
      atomicAdd(&csq[n0 + ct * 16 + l16], cq);
    }
  }
}

// ---------------------------------------------------------------------------
// Whitening stats finalize.
// ---------------------------------------------------------------------------
__global__ void stats_kernel(const float* __restrict__ colsum,
                             const float* __restrict__ colsumsq,
                             float* __restrict__ meanv, float* __restrict__ invsd)
{
  int i = threadIdx.x;
  if (i < 3 * DOUT) {
    float mu  = colsum[i] / (float)NROWS;
    float var = (colsumsq[i] - (float)NROWS * mu * mu) / (float)(NROWS - 1);
    float sd  = sqrtf(fmaxf(var, 0.0f)) + 1e-5f;
    meanv[i] = mu;
    invsd[i] = 1.0f / sd;
  }
}

// ---------------------------------------------------------------------------
// Whiten + L2-normalize + pos dots (fp32) + bf16 z (plain V + log2e-scaled U).
// ---------------------------------------------------------------------------
__global__ __launch_bounds__(128) void whiten_kernel(
    const float* __restrict__ y3,
    const float* __restrict__ meanv, const float* __restrict__ invsd,
    ushort_t* __restrict__ zB, ushort_t* __restrict__ zE,
    ushort_t* __restrict__ zF,
    ushort_t* __restrict__ zBs, ushort_t* __restrict__ zEs,
    float* __restrict__ pos)
{
  int row = blockIdx.x, t = threadIdx.x;
  size_t off = (size_t)row * DOUT + t;
  const size_t hs = (size_t)NROWS * DOUT;
  float vB = (y3[off]          - meanv[t])            * invsd[t];
  float vE = (y3[off + hs]     - meanv[DOUT + t])     * invsd[DOUT + t];
  float vF = (y3[off + 2 * hs] - meanv[2 * DOUT + t]) * invsd[2 * DOUT + t];

  __shared__ float red[6], red2[6];
  float nB = vB * vB, nE = vE * vE, nF = vF * vF;
#pragma unroll
  for (int o = 32; o > 0; o >>= 1) {
    nB += __shfl_down(nB, o, 64);
    nE += __shfl_down(nE, o, 64);
    nF += __shfl_down(nF, o, 64);
  }
  int lane = t & 63, wv = t >> 6;
  if (lane == 0) { red[wv * 3] = nB; red[wv * 3 + 1] = nE; red[wv * 3 + 2] = nF; }
  __syncthreads();
  float iB = 1.0f / fmaxf(sqrtf(red[0] + red[3]), 1e-12f);
  float iE = 1.0f / fmaxf(sqrtf(red[1] + red[4]), 1e-12f);
  float iF = 1.0f / fmaxf(sqrtf(red[2] + red[5]), 1e-12f);
  float zb = vB * iB, ze = vE * iE, zf = vF * iF;

  zB[off]  = (ushort_t)f2bf(zb);
  zE[off]  = (ushort_t)f2bf(ze);
  zF[off]  = (ushort_t)f2bf(zf);
  zBs[off] = (ushort_t)f2bf(zb * LOG2E);
  zEs[off] = (ushort_t)f2bf(ze * LOG2E);

  float pBE = zb * ze, pBF = zb * zf, pEF = ze * zf;
#pragma unroll
  for (int o = 32; o > 0; o >>= 1) {
    pBE += __shfl_down(pBE, o, 64);
    pBF += __shfl_down(pBF, o, 64);
    pEF += __shfl_down(pEF, o, 64);
  }
  if (lane == 0) { red2[wv * 3] = pBE; red2[wv * 3 + 1] = pBF; red2[wv * 3 + 2] = pEF; }
  __syncthreads();
  if (t == 0) {
    pos[row]             = red2[0] + red2[3];
    pos[NROWS + row]     = red2[1] + red2[4];
    pos[2 * NROWS + row] = red2[2] + red2[5];
  }
}

// ---------------------------------------------------------------------------
// Gram v4: rowsum_i += sum_j exp2(Us_i . V_j), 5 combos.
// Block = 4 waves STACKED in m (256 rows), all sharing the same 64-col
// V-tiles -> V hits L1 for 3 of 4 waves. Per wave: 64 rows (RT=4) x
// 64 cols (CT=4), NT=8 n-tiles. b double-buffered (prefetch next ki /
// next nt). Raw s_barrier per nt keeps waves converged for L1 reuse
// (registers only -> no correctness dependence, no waitcnt drain).
// grid (32, 16, 5).
// ---------------------------------------------------------------------------
#define GRAM_NT 8
__global__ __launch_bounds__(256) void gram_kernel(
    const ushort_t* __restrict__ zB, const ushort_t* __restrict__ zE,
    const ushort_t* __restrict__ zF,
    const ushort_t* __restrict__ zBs, const ushort_t* __restrict__ zEs,
    float* __restrict__ rowsum)
{
  const ushort_t *U, *V;
  float* rs;
  switch (blockIdx.z) {
    case 0:  U = zBs; V = zB; rs = rowsum;             break;
    case 1:  U = zEs; V = zE; rs = rowsum + NROWS;     break;
    case 2:  U = zBs; V = zE; rs = rowsum + 2 * NROWS; break;
    case 3:  U = zBs; V = zF; rs = rowsum + 3 * NROWS; break;
    default: U = zEs; V = zF; rs = rowsum + 4 * NROWS; break;
  }

  const int tid = threadIdx.x, lane = tid & 63, wave = tid >> 6;
  const int quad = lane >> 4, l16 = lane & 15;
  const int m0 = blockIdx.x * 256 + wave * 64;     // waves stacked in m
  const int nbase = blockIdx.y * (64 * GRAM_NT);   // shared across waves

  // cache this wave's A fragments: 64 rows x 128 k (16 frags = 64 VGPR)
  const ushort_t* ua = U + (size_t)(m0 + l16) * DOUT + quad * 8;
  bf16x8 a[4][4];
#pragma unroll
  for (int rt = 0; rt < 4; rt++)
#pragma unroll
    for (int ki = 0; ki < 4; ki++)
      a[rt][ki] = *(const bf16x8*)(ua + rt * 16 * DOUT + ki * 32);

  const ushort_t* vb0 = V + (size_t)(nbase + l16) * DOUT + quad * 8;

  float rsum[4][4] = {};
  bf16x8 b[2][4];
#pragma unroll
  for (int ct = 0; ct < 4; ct++) b[0][ct] = *(const bf16x8*)(vb0 + ct * 16 * DOUT);

  for (int nt = 0; nt < GRAM_NT; nt++) {
    const ushort_t* vb = vb0 + (size_t)nt * 64 * DOUT;
    f32x4 acc[4][4];
#pragma unroll
    for (int ki = 0; ki < 4; ki++) {
      const int cur = ki & 1;
      // prefetch next ki (or next nt's ki=0) into the other buffer
      if (ki < 3) {
        const ushort_t* nb = vb + (ki + 1) * 32;
#pragma unroll
        for (int ct = 0; ct < 4; ct++)
          b[cur ^ 1][ct] = *(const bf16x8*)(nb + ct * 16 * DOUT);
      } else if (nt < GRAM_NT - 1) {
        const ushort_t* nb = vb0 + (size_t)(nt + 1) * 64 * DOUT;
#pragma unroll
        for (int ct = 0; ct < 4; ct++)
          b[cur ^ 1][ct] = *(const bf16x8*)(nb + ct * 16 * DOUT);
      }
      if (ki == 0) {
        const f32x4 zero = {0.0f, 0.0f, 0.0f, 0.0f};
#pragma unroll
        for (int rt = 0; rt < 4; rt++)
#pragma unroll
          for (int ct = 0; ct < 4; ct++)
            acc[rt][ct] = __builtin_amdgcn_mfma_f32_16x16x32_bf16(
                a[rt][0], b[cur][ct], zero, 0, 0, 0);
      } else {
#pragma unroll
        for (int rt = 0; rt < 4; rt++)
#pragma unroll
          for (int ct = 0; ct < 4; ct++)
            acc[rt][ct] = __builtin_amdgcn_mfma_f32_16x16x32_bf16(
                a[rt][ki], b[cur][ct], acc[rt][ct], 0, 0, 0);
      }
    }
    // exp2 + in-register row accumulation (prefetched loads fly underneath)
#pragma unroll
    for (int rt = 0; rt < 4; rt++)
#pragma unroll
      for (int reg = 0; reg < 4; reg++)
        rsum[rt][reg] += FAST_EXP2(acc[rt][0][reg]) + FAST_EXP2(acc[rt][1][reg]) +
                         FAST_EXP2(acc[rt][2][reg]) + FAST_EXP2(acc[rt][3][reg]);
    __builtin_amdgcn_s_barrier();  // pacing only: keep waves' V-reads in L1
  }

#pragma unroll
  for (int rt = 0; rt < 4; rt++)
#pragma unroll
    for (int reg = 0; reg < 4; reg++) {
      float s = rsum[rt][reg];
      s += __shfl_xor(s, 1, 64);
      s += __shfl_xor(s, 2, 64);
      s += __shfl_xor(s, 4, 64);
      s += __shfl_xor(s, 8, 64);
      if (l16 == 0)
        atomicAdd(&rs[m0 + rt * 16 + quad * 4 + reg], s);
    }
}

// ---------------------------------------------------------------------------
// Final loss. logits[i,i] masked to 0: self + (1 - e).
// ---------------------------------------------------------------------------
__global__ __launch_bounds__(1024) void loss_kernel(
    const float* __restrict__ rowsum, const float* __restrict__ pos,
    float* __restrict__ out)
{
  const float* sB  = rowsum;
  const float* sE  = rowsum + NROWS;
  const float* cBE = rowsum + 2 * NROWS;
  const float* cBF = rowsum + 3 * NROWS;
  const float* cEF = rowsum + 4 * NROWS;
  const float* pBE = pos;
  const float* pBF = pos + NROWS;
  const float* pEF = pos + 2 * NROWS;

  const float corr = 1.0f - expf(1.0f);
  float local = 0.0f;
  for (int i = threadIdx.x; i < NROWS; i += 1024) {
    float selB = sB[i] + corr;
    float selE = sE[i] + corr;
    local += __logf(selB + cBE[i]) - pBE[i];
    local += __logf(selB + cBF[i]) - pBF[i];
    local += __logf(selE + cEF[i]) - pEF[i];
  }
  __shared__ float red[16];
#pragma unroll
  for (int o = 32; o > 0; o >>= 1) local += __shfl_down(local, o, 64);
  int lane = threadIdx.x & 63, wv = threadIdx.x >> 6;
  if (lane == 0) red[wv] = local;
  __syncthreads();
  if (threadIdx.x == 0) {
    float t = 0.0f;
#pragma unroll
    for (int w = 0; w < 16; w++) t += red[w];
    out[0] = t / (3.0f * (float)NROWS);
  }
}

// ---------------------------------------------------------------------------
extern "C" void kernel_launch(void* const* d_in, const int* in_sizes, int n_in,
                              void* d_out, int out_size, void* d_ws, size_t ws_size,
                              hipStream_t stream)
{
  const float* xs[3] = {(const float*)d_in[0], (const float*)d_in[1], (const float*)d_in[2]};
  const float* W1[3] = {(const float*)d_in[3], (const float*)d_in[7],  (const float*)d_in[11]};
  const float* b1[3] = {(const float*)d_in[4], (const float*)d_in[8],  (const float*)d_in[12]};
  const float* W2[3] = {(const float*)d_in[5], (const float*)d_in[9],  (const float*)d_in[13]};
  const float* b2[3] = {(const float*)d_in[6], (const float*)d_in[10], (const float*)d_in[14]};

  float* ws = (float*)d_ws;
  // workspace layout (float offsets):
  float* colsum   = ws;            // 384   [zeroed]
  float* colsumsq = ws + 384;      // 384   [zeroed]
  float* rowsum   = ws + 768;      // 5*8192 [zeroed]
  float* meanv    = ws + 41728;    // 384
  float* invsd    = ws + 42112;    // 384
  float* pos      = ws + 42496;    // 3*8192 -> ends 67072
  ushort_t* w1t3 = (ushort_t*)(ws + 67072);    // 3*256*512 bf16 = 196608 fl
  ushort_t* w2t3 = (ushort_t*)(ws + 263680);   // 3*128*256 bf16 = 49152 fl
  ushort_t* h3   = (ushort_t*)(ws + 312832);   // 3*8192*256 bf16 = 3145728 fl
  float*    y3   = ws + 3458560;               // 3*8192*128 fp32 = 3145728 fl
  // z buffers overlay h3 (dead after gemm2): 5 x 8192*128 bf16
  ushort_t* zB  = (ushort_t*)(ws + 312832);
  ushort_t* zE  = zB  + (size_t)NROWS * DOUT;
  ushort_t* zF  = zE  + (size_t)NROWS * DOUT;
  ushort_t* zBs = zF  + (size_t)NROWS * DOUT;
  ushort_t* zEs = zBs + (size_t)NROWS * DOUT;
  // peak ws usage: 6,604,288 floats = 26.4 MB

  hipMemsetAsync(ws, 0, 41728 * sizeof(float), stream);

  prep_w_kernel<<<dim3(640, 3), 256, 0, stream>>>(
      W1[0], W1[1], W1[2], W2[0], W2[1], W2[2], w1t3, w2t3);
  gemm1_kernel<<<dim3(128, 2, 3), 256, 0, stream>>>(
      xs[0], xs[1], xs[2], w1t3, b1[0], b1[1], b1[2], h3);
  gemm2_kernel<<<dim3(256, 1, 3), 256, 0, stream>>>(
      h3, w2t3, b2[0], b2[1], b2[2], y3, colsum, colsumsq);
  stats_kernel<<<1, 3 * DOUT, 0, stream>>>(colsum, colsumsq, meanv, invsd);
  whiten_kernel<<<NROWS, 128, 0, stream>>>(
      y3, meanv, invsd, zB, zE, zF, zBs, zEs, pos);
  gram_kernel<<<dim3(32, 16, 5), 256, 0, stream>>>(zB, zE, zF, zBs, zEs, rowsum);
  loss_kernel<<<1, 1024, 0, stream>>>(rowsum, pos, (float*)d_out);
}

// Round 5
// 408.780 us; speedup vs baseline: 1.0428x; 1.0428x over previous
//
#include <hip/hip_runtime.h>
#include <hip/hip_bf16.h>
#include <math.h>

#define NROWS 8192
#define DIN   512
#define DHID  256
#define DOUT  128
#define LOG2E 1.4426950408889634f

typedef unsigned short ushort_t;
typedef __attribute__((ext_vector_type(8))) short bf16x8;
typedef __attribute__((ext_vector_type(4))) float f32x4;

#if defined(__has_builtin)
#  if __has_builtin(__builtin_amdgcn_exp2f)
#    define FAST_EXP2(x) __builtin_amdgcn_exp2f(x)
#  else
#    define FAST_EXP2(x) exp2f(x)
#  endif
#else
#  define FAST_EXP2(x) exp2f(x)
#endif

__device__ __forceinline__ short f2bf(float x) {
  __hip_bfloat16 h = __float2bfloat16(x);
  return *(short*)&h;
}

__device__ __forceinline__ bf16x8 cvt8(float4 lo, float4 hi) {
  bf16x8 r;
  r[0] = f2bf(lo.x); r[1] = f2bf(lo.y); r[2] = f2bf(lo.z); r[3] = f2bf(lo.w);
  r[4] = f2bf(hi.x); r[5] = f2bf(hi.y); r[6] = f2bf(hi.z); r[7] = f2bf(hi.w);
  return r;
}

// ---------------------------------------------------------------------------
// Weight prep (all 3 heads): W1 (512x256)->w1t (256x512), W2 (256x128)->
// w2t (128x256), fp32 -> bf16, transposed so k is contiguous. grid (640, 3).
// ---------------------------------------------------------------------------
__global__ __launch_bounds__(256) void prep_w_kernel(
    const float* __restrict__ W1_0, const float* __restrict__ W1_1,
    const float* __restrict__ W1_2,
    const float* __restrict__ W2_0, const float* __restrict__ W2_1,
    const float* __restrict__ W2_2,
    ushort_t* __restrict__ w1t3, ushort_t* __restrict__ w2t3)
{
  const float* W1s[3] = {W1_0, W1_1, W1_2};
  const float* W2s[3] = {W2_0, W2_1, W2_2};
  const int z = blockIdx.y;
  int idx = blockIdx.x * 256 + threadIdx.x;
  if (idx < DHID * DIN) {
    int n = idx >> 9, k = idx & (DIN - 1);
    w1t3[(size_t)z * DHID * DIN + idx] = f2bf(W1s[z][(size_t)k * DHID + n]);
  } else {
    int j = idx - DHID * DIN;
    int n = j >> 8, k = j & (DHID - 1);
    w2t3[(size_t)z * DOUT * DHID + j] = f2bf(W2s[z][(size_t)k * DOUT + n]);
  }
}

// ---------------------------------------------------------------------------
// GEMM1 (all heads): H = relu(x @ W1 + b1). x fp32 loaded directly and
// converted in-register. Block 64x128 (waves 2x2, wave 32x64). K=512, 16 ki,
// ki-prefetched. grid (128, 2, 3).
// ---------------------------------------------------------------------------
__global__ __launch_bounds__(256) void gemm1_kernel(
    const float* __restrict__ x0, const float* __restrict__ x1,
    const float* __restrict__ x2,
    const ushort_t* __restrict__ w1t3,
    const float* __restrict__ b1_0, const float* __restrict__ b1_1,
    const float* __restrict__ b1_2,
    ushort_t* __restrict__ h3)
{
  const float* xs[3] = {x0, x1, x2};
  const float* bs[3] = {b1_0, b1_1, b1_2};
  const int z = blockIdx.z;
  const float* X = xs[z];
  const ushort_t* Bt = w1t3 + (size_t)z * DHID * DIN;
  ushort_t* H = h3 + (size_t)z * NROWS * DHID;

  const int tid = threadIdx.x, lane = tid & 63, wave = tid >> 6;
  const int wr = wave >> 1, wc = wave & 1, quad = lane >> 4, l16 = lane & 15;
  const int m0 = blockIdx.x * 64 + wr * 32;
  const int n0 = blockIdx.y * 128 + wc * 64;

  const float* px = X + (size_t)(m0 + l16) * DIN + quad * 8;
  const ushort_t* pb = Bt + (size_t)(n0 + l16) * DIN + quad * 8;

  f32x4 acc[2][4] = {};
  float4 af[2][2][2];
  bf16x8 b[2][4];
#pragma unroll
  for (int rt = 0; rt < 2; rt++) {
    af[0][rt][0] = *(const float4*)(px + rt * 16 * DIN);
    af[0][rt][1] = *(const float4*)(px + rt * 16 * DIN + 4);
  }
#pragma unroll
  for (int ct = 0; ct < 4; ct++) b[0][ct] = *(const bf16x8*)(pb + ct * 16 * DIN);

#pragma unroll
  for (int ki = 0; ki < 16; ki++) {
    const int cur = ki & 1;
    if (ki < 15) {
      const int off = (ki + 1) * 32;
#pragma unroll
      for (int rt = 0; rt < 2; rt++) {
        af[cur ^ 1][rt][0] = *(const float4*)(px + rt * 16 * DIN + off);
        af[cur ^ 1][rt][1] = *(const float4*)(px + rt * 16 * DIN + off + 4);
      }
#pragma unroll
      for (int ct = 0; ct < 4; ct++)
        b[cur ^ 1][ct] = *(const bf16x8*)(pb + ct * 16 * DIN + off);
    }
    bf16x8 a[2];
#pragma unroll
    for (int rt = 0; rt < 2; rt++) a[rt] = cvt8(af[cur][rt][0], af[cur][rt][1]);
#pragma unroll
    for (int rt = 0; rt < 2; rt++)
#pragma unroll
      for (int ct = 0; ct < 4; ct++)
        acc[rt][ct] = __builtin_amdgcn_mfma_f32_16x16x32_bf16(
            a[rt], b[cur][ct], acc[rt][ct], 0, 0, 0);
  }

  float bb[4];
#pragma unroll
  for (int ct = 0; ct < 4; ct++) bb[ct] = bs[z][n0 + ct * 16 + l16];
#pragma unroll
  for (int rt = 0; rt < 2; rt++)
#pragma unroll
    for (int ct = 0; ct < 4; ct++)
#pragma unroll
      for (int reg = 0; reg < 4; reg++) {
        float v = fmaxf(acc[rt][ct][reg] + bb[ct], 0.0f);
        H[(size_t)(m0 + rt * 16 + quad * 4 + reg) * DHID + n0 + ct * 16 + l16] =
            (ushort_t)f2bf(v);
      }
}

// ---------------------------------------------------------------------------
// GEMM2 (all heads): Y = H @ W2 + b2 (fp32) + column sum/sumsq atomics.
// Block 32x128 (waves 2x2, wave 16x64). K=256, 8 ki, prefetched.
// grid (256, 1, 3).
// ---------------------------------------------------------------------------
__global__ __launch_bounds__(256) void gemm2_kernel(
    const ushort_t* __restrict__ h3, const ushort_t* __restrict__ w2t3,
    const float* __restrict__ b2_0, const float* __restrict__ b2_1,
    const float* __restrict__ b2_2,
    float* __restrict__ y3,
    float* __restrict__ colsum, float* __restrict__ colsumsq)
{
  const float* bs[3] = {b2_0, b2_1, b2_2};
  const int z = blockIdx.z;
  const ushort_t* A = h3 + (size_t)z * NROWS * DHID;
  const ushort_t* Bt = w2t3 + (size_t)z * DOUT * DHID;
  float* Y = y3 + (size_t)z * NROWS * DOUT;
  float* csum = colsum + z * DOUT;
  float* csq  = colsumsq + z * DOUT;

  const int tid = threadIdx.x, lane = tid & 63, wave = tid >> 6;
  const int wr = wave >> 1, wc = wave & 1, quad = lane >> 4, l16 = lane & 15;
  const int m0 = blockIdx.x * 32 + wr * 16;
  const int n0 = wc * 64;

  const ushort_t* pa = A + (size_t)(m0 + l16) * DHID + quad * 8;
  const ushort_t* pb = Bt + (size_t)(n0 + l16) * DHID + quad * 8;

  f32x4 acc[4] = {};
  bf16x8 a[2], b[2][4];
  a[0] = *(const bf16x8*)pa;
#pragma unroll
  for (int ct = 0; ct < 4; ct++) b[0][ct] = *(const bf16x8*)(pb + ct * 16 * DHID);

#pragma unroll
  for (int ki = 0; ki < 8; ki++) {
    const int cur = ki & 1;
    if (ki < 7) {
      const int off = (ki + 1) * 32;
      a[cur ^ 1] = *(const bf16x8*)(pa + off);
#pragma unroll
      for (int ct = 0; ct < 4; ct++)
        b[cur ^ 1][ct] = *(const bf16x8*)(pb + ct * 16 * DHID + off);
    }
#pragma unroll
    for (int ct = 0; ct < 4; ct++)
      acc[ct] = __builtin_amdgcn_mfma_f32_16x16x32_bf16(
          a[cur], b[cur][ct], acc[ct], 0, 0, 0);
  }

  float bb[4];
#pragma unroll
  for (int ct = 0; ct < 4; ct++) bb[ct] = bs[z][n0 + ct * 16 + l16];
#pragma unroll
  for (int ct = 0; ct < 4; ct++) {
    float cs = 0.0f, cq = 0.0f;
#pragma unroll
    for (int reg = 0; reg < 4; reg++) {
      float v = acc[ct][reg] + bb[ct];
      Y[(size_t)(m0 + quad * 4 + reg) * DOUT + n0 + ct * 16 + l16] = v;
      cs += v; cq += v * v;
    }
    cs += __shfl_xor(cs, 16, 64); cs += __shfl_xor(cs, 32, 64);
    cq += __shfl_xor(cq, 16, 64); cq += __shfl_xor(cq, 32, 64);
    if (lane < 16) {
      atomicAdd(&csum[n0 + ct * 16 + l16], cs);
      atomicAdd(&csq[n0 + ct * 16 + l16], cq);
    }
  }
}

// ---------------------------------------------------------------------------
// Whitening stats finalize.
// ---------------------------------------------------------------------------
__global__ void stats_kernel(const float* __restrict__ colsum,
                             const float* __restrict__ colsumsq,
                             float* __restrict__ meanv, float* __restrict__ invsd)
{
  int i = threadIdx.x;
  if (i < 3 * DOUT) {
    float mu  = colsum[i] / (float)NROWS;
    float var = (colsumsq[i] - (float)NROWS * mu * mu) / (float)(NROWS - 1);
    float sd  = sqrtf(fmaxf(var, 0.0f)) + 1e-5f;
    meanv[i] = mu;
    invsd[i] = 1.0f / sd;
  }
}

// ---------------------------------------------------------------------------
// Whiten + L2-normalize + pos dots (fp32) + bf16 z (plain V + log2e-scaled U).
// ---------------------------------------------------------------------------
__global__ __launch_bounds__(128) void whiten_kernel(
    const float* __restrict__ y3,
    const float* __restrict__ meanv, const float* __restrict__ invsd,
    ushort_t* __restrict__ zB, ushort_t* __restrict__ zE,
    ushort_t* __restrict__ zF,
    ushort_t* __restrict__ zBs, ushort_t* __restrict__ zEs,
    float* __restrict__ pos)
{
  int row = blockIdx.x, t = threadIdx.x;
  size_t off = (size_t)row * DOUT + t;
  const size_t hs = (size_t)NROWS * DOUT;
  float vB = (y3[off]          - meanv[t])            * invsd[t];
  float vE = (y3[off + hs]     - meanv[DOUT + t])     * invsd[DOUT + t];
  float vF = (y3[off + 2 * hs] - meanv[2 * DOUT + t]) * invsd[2 * DOUT + t];

  __shared__ float red[6], red2[6];
  float nB = vB * vB, nE = vE * vE, nF = vF * vF;
#pragma unroll
  for (int o = 32; o > 0; o >>= 1) {
    nB += __shfl_down(nB, o, 64);
    nE += __shfl_down(nE, o, 64);
    nF += __shfl_down(nF, o, 64);
  }
  int lane = t & 63, wv = t >> 6;
  if (lane == 0) { red[wv * 3] = nB; red[wv * 3 + 1] = nE; red[wv * 3 + 2] = nF; }
  __syncthreads();
  float iB = 1.0f / fmaxf(sqrtf(red[0] + red[3]), 1e-12f);
  float iE = 1.0f / fmaxf(sqrtf(red[1] + red[4]), 1e-12f);
  float iF = 1.0f / fmaxf(sqrtf(red[2] + red[5]), 1e-12f);
  float zb = vB * iB, ze = vE * iE, zf = vF * iF;

  zB[off]  = (ushort_t)f2bf(zb);
  zE[off]  = (ushort_t)f2bf(ze);
  zF[off]  = (ushort_t)f2bf(zf);
  zBs[off] = (ushort_t)f2bf(zb * LOG2E);
  zEs[off] = (ushort_t)f2bf(ze * LOG2E);

  float pBE = zb * ze, pBF = zb * zf, pEF = ze * zf;
#pragma unroll
  for (int o = 32; o > 0; o >>= 1) {
    pBE += __shfl_down(pBE, o, 64);
    pBF += __shfl_down(pBF, o, 64);
    pEF += __shfl_down(pEF, o, 64);
  }
  if (lane == 0) { red2[wv * 3] = pBE; red2[wv * 3 + 1] = pBF; red2[wv * 3 + 2] = pEF; }
  __syncthreads();
  if (t == 0) {
    pos[row]             = red2[0] + red2[3];
    pos[NROWS + row]     = red2[1] + red2[4];
    pos[2 * NROWS + row] = red2[2] + red2[5];
  }
}

// ---------------------------------------------------------------------------
// Gram v5: rowsum_i += sum_j exp2(Us_i . V_j), 5 combos.
// Block = 4 waves stacked in m (256 rows), NO barrier. Each wave: 64 rows x
// 512 cols, processed as 16 chunks of 32 cols. Software pipeline within the
// wave: two acc buffers (chunk pair) -> the exp2 epilogue of chunk c-1 runs
// on the VALU pipe while the MFMA pipe fills chunk c, and the 8 b-fragment
// loads for chunk c+1 are issued a full chunk (~600 cyc) ahead of use.
// All buffer indices compile-time (pair loop). grid (32, 16, 5).
// ---------------------------------------------------------------------------
#define G_CH 16  // 32-col chunks per block
__global__ __launch_bounds__(256) void gram_kernel(
    const ushort_t* __restrict__ zB, const ushort_t* __restrict__ zE,
    const ushort_t* __restrict__ zF,
    const ushort_t* __restrict__ zBs, const ushort_t* __restrict__ zEs,
    float* __restrict__ rowsum)
{
  const ushort_t *U, *V;
  float* rs;
  switch (blockIdx.z) {
    case 0:  U = zBs; V = zB; rs = rowsum;             break;
    case 1:  U = zEs; V = zE; rs = rowsum + NROWS;     break;
    case 2:  U = zBs; V = zE; rs = rowsum + 2 * NROWS; break;
    case 3:  U = zBs; V = zF; rs = rowsum + 3 * NROWS; break;
    default: U = zEs; V = zF; rs = rowsum + 4 * NROWS; break;
  }

  const int tid = threadIdx.x, lane = tid & 63, wave = tid >> 6;
  const int quad = lane >> 4, l16 = lane & 15;
  const int m0 = blockIdx.x * 256 + wave * 64;     // waves stacked in m
  const int nbase = blockIdx.y * (32 * G_CH);

  // cache this wave's A fragments: 64 rows x 128 k (16 frags = 64 VGPR)
  const ushort_t* ua = U + (size_t)(m0 + l16) * DOUT + quad * 8;
  bf16x8 a[4][4];
#pragma unroll
  for (int rt = 0; rt < 4; rt++)
#pragma unroll
    for (int ki = 0; ki < 4; ki++)
      a[rt][ki] = *(const bf16x8*)(ua + rt * 16 * DOUT + ki * 32);

  const ushort_t* vb0 = V + (size_t)(nbase + l16) * DOUT + quad * 8;

  float rsum[4][4] = {};
  bf16x8 b[2][4][2];   // [buf][ki][ct]
  f32x4 acc[2][4][2];  // [buf][rt][ct]
  const f32x4 zero = {0.0f, 0.0f, 0.0f, 0.0f};

  // prime chunk 0 -> b[0]
#pragma unroll
  for (int ki = 0; ki < 4; ki++)
#pragma unroll
    for (int ct = 0; ct < 2; ct++)
      b[0][ki][ct] = *(const bf16x8*)(vb0 + (size_t)(ct * 16) * DOUT + ki * 32);

  for (int cp = 0; cp < G_CH / 2; cp++) {
    const ushort_t* vbo = vb0 + (size_t)(cp * 64 + 32) * DOUT;  // odd chunk
    // prefetch odd chunk -> b[1]
#pragma unroll
    for (int ki = 0; ki < 4; ki++)
#pragma unroll
      for (int ct = 0; ct < 2; ct++)
        b[1][ki][ct] = *(const bf16x8*)(vbo + (size_t)(ct * 16) * DOUT + ki * 32);
    // MFMA even chunk from b[0] -> acc[0]
#pragma unroll
    for (int ki = 0; ki < 4; ki++)
#pragma unroll
      for (int rt = 0; rt < 4; rt++)
#pragma unroll
        for (int ct = 0; ct < 2; ct++)
          acc[0][rt][ct] = __builtin_amdgcn_mfma_f32_16x16x32_bf16(
              a[rt][ki], b[0][ki][ct],
              ki == 0 ? zero : acc[0][rt][ct], 0, 0, 0);
    // exp2 epilogue of previous pair's odd chunk (acc[1]); overlaps MFMAs
    if (cp) {
#pragma unroll
      for (int rt = 0; rt < 4; rt++)
#pragma unroll
        for (int ct = 0; ct < 2; ct++)
#pragma unroll
          for (int reg = 0; reg < 4; reg++)
            rsum[rt][reg] += FAST_EXP2(acc[1][rt][ct][reg]);
    }
    // prefetch next pair's even chunk -> b[0]
    if (cp + 1 < G_CH / 2) {
      const ushort_t* vbe = vb0 + (size_t)(cp * 64 + 64) * DOUT;
#pragma unroll
      for (int ki = 0; ki < 4; ki++)
#pragma unroll
        for (int ct = 0; ct < 2; ct++)
          b[0][ki][ct] = *(const bf16x8*)(vbe + (size_t)(ct * 16) * DOUT + ki * 32);
    }
    // MFMA odd chunk from b[1] -> acc[1]
#pragma unroll
    for (int ki = 0; ki < 4; ki++)
#pragma unroll
      for (int rt = 0; rt < 4; rt++)
#pragma unroll
        for (int ct = 0; ct < 2; ct++)
          acc[1][rt][ct] = __builtin_amdgcn_mfma_f32_16x16x32_bf16(
              a[rt][ki], b[1][ki][ct],
              ki == 0 ? zero : acc[1][rt][ct], 0, 0, 0);
    // exp2 epilogue of even chunk (acc[0]); overlaps odd-chunk MFMAs
#pragma unroll
    for (int rt = 0; rt < 4; rt++)
#pragma unroll
      for (int ct = 0; ct < 2; ct++)
#pragma unroll
        for (int reg = 0; reg < 4; reg++)
          rsum[rt][reg] += FAST_EXP2(acc[0][rt][ct][reg]);
  }
  // tail: last odd chunk
#pragma unroll
  for (int rt = 0; rt < 4; rt++)
#pragma unroll
    for (int ct = 0; ct < 2; ct++)
#pragma unroll
      for (int reg = 0; reg < 4; reg++)
        rsum[rt][reg] += FAST_EXP2(acc[1][rt][ct][reg]);

  // one cross-lane reduction over l16 + one atomic per row per block
#pragma unroll
  for (int rt = 0; rt < 4; rt++)
#pragma unroll
    for (int reg = 0; reg < 4; reg++) {
      float s = rsum[rt][reg];
      s += __shfl_xor(s, 1, 64);
      s += __shfl_xor(s, 2, 64);
      s += __shfl_xor(s, 4, 64);
      s += __shfl_xor(s, 8, 64);
      if (l16 == 0)
        atomicAdd(&rs[m0 + rt * 16 + quad * 4 + reg], s);
    }
}

// ---------------------------------------------------------------------------
// Final loss. logits[i,i] masked to 0: self + (1 - e).
// ---------------------------------------------------------------------------
__global__ __launch_bounds__(1024) void loss_kernel(
    const float* __restrict__ rowsum, const float* __restrict__ pos,
    float* __restrict__ out)
{
  const float* sB  = rowsum;
  const float* sE  = rowsum + NROWS;
  const float* cBE = rowsum + 2 * NROWS;
  const float* cBF = rowsum + 3 * NROWS;
  const float* cEF = rowsum + 4 * NROWS;
  const float* pBE = pos;
  const float* pBF = pos + NROWS;
  const float* pEF = pos + 2 * NROWS;

  const float corr = 1.0f - expf(1.0f);
  float local = 0.0f;
  for (int i = threadIdx.x; i < NROWS; i += 1024) {
    float selB = sB[i] + corr;
    float selE = sE[i] + corr;
    local += __logf(selB + cBE[i]) - pBE[i];
    local += __logf(selB + cBF[i]) - pBF[i];
    local += __logf(selE + cEF[i]) - pEF[i];
  }
  __shared__ float red[16];
#pragma unroll
  for (int o = 32; o > 0; o >>= 1) local += __shfl_down(local, o, 64);
  int lane = threadIdx.x & 63, wv = threadIdx.x >> 6;
  if (lane == 0) red[wv] = local;
  __syncthreads();
  if (threadIdx.x == 0) {
    float t = 0.0f;
#pragma unroll
    for (int w = 0; w < 16; w++) t += red[w];
    out[0] = t / (3.0f * (float)NROWS);
  }
}

// ---------------------------------------------------------------------------
extern "C" void kernel_launch(void* const* d_in, const int* in_sizes, int n_in,
                              void* d_out, int out_size, void* d_ws, size_t ws_size,
                              hipStream_t stream)
{
  const float* xs[3] = {(const float*)d_in[0], (const float*)d_in[1], (const float*)d_in[2]};
  const float* W1[3] = {(const float*)d_in[3], (const float*)d_in[7],  (const float*)d_in[11]};
  const float* b1[3] = {(const float*)d_in[4], (const float*)d_in[8],  (const float*)d_in[12]};
  const float* W2[3] = {(const float*)d_in[5], (const float*)d_in[9],  (const float*)d_in[13]};
  const float* b2[3] = {(const float*)d_in[6], (const float*)d_in[10], (const float*)d_in[14]};

  float* ws = (float*)d_ws;
  // workspace layout (float offsets):
  float* colsum   = ws;            // 384   [zeroed]
  float* colsumsq = ws + 384;      // 384   [zeroed]
  float* rowsum   = ws + 768;      // 5*8192 [zeroed]
  float* meanv    = ws + 41728;    // 384
  float* invsd    = ws + 42112;    // 384
  float* pos      = ws + 42496;    // 3*8192 -> ends 67072
  ushort_t* w1t3 = (ushort_t*)(ws + 67072);    // 3*256*512 bf16 = 196608 fl
  ushort_t* w2t3 = (ushort_t*)(ws + 263680);   // 3*128*256 bf16 = 49152 fl
  ushort_t* h3   = (ushort_t*)(ws + 312832);   // 3*8192*256 bf16 = 3145728 fl
  float*    y3   = ws + 3458560;               // 3*8192*128 fp32 = 3145728 fl
  // z buffers overlay h3 (dead after gemm2): 5 x 8192*128 bf16
  ushort_t* zB  = (ushort_t*)(ws + 312832);
  ushort_t* zE  = zB  + (size_t)NROWS * DOUT;
  ushort_t* zF  = zE  + (size_t)NROWS * DOUT;
  ushort_t* zBs = zF  + (size_t)NROWS * DOUT;
  ushort_t* zEs = zBs + (size_t)NROWS * DOUT;
  // peak ws usage: 6,604,288 floats = 26.4 MB

  hipMemsetAsync(ws, 0, 41728 * sizeof(float), stream);

  prep_w_kernel<<<dim3(640, 3), 256, 0, stream>>>(
      W1[0], W1[1], W1[2], W2[0], W2[1], W2[2], w1t3, w2t3);
  gemm1_kernel<<<dim3(128, 2, 3), 256, 0, stream>>>(
      xs[0], xs[1], xs[2], w1t3, b1[0], b1[1], b1[2], h3);
  gemm2_kernel<<<dim3(256, 1, 3), 256, 0, stream>>>(
      h3, w2t3, b2[0], b2[1], b2[2], y3, colsum, colsumsq);
  stats_kernel<<<1, 3 * DOUT, 0, stream>>>(colsum, colsumsq, meanv, invsd);
  whiten_kernel<<<NROWS, 128, 0, stream>>>(
      y3, meanv, invsd, zB, zE, zF, zBs, zEs, pos);
  gram_kernel<<<dim3(32, 16, 5), 256, 0, stream>>>(zB, zE, zF, zBs, zEs, rowsum);
  loss_kernel<<<1, 1024, 0, stream>>>(rowsum, pos, (float*)d_out);
}

// Round 6
// 296.872 us; speedup vs baseline: 1.4359x; 1.3770x over previous
//
#include <hip/hip_runtime.h>
#include <hip/hip_bf16.h>
#include <math.h>

#define NROWS 8192
#define DIN   512
#define DHID  256
#define DOUT  128
#define LOG2E 1.4426950408889634f

typedef unsigned short ushort_t;
typedef __attribute__((ext_vector_type(8))) short bf16x8;
typedef __attribute__((ext_vector_type(4))) float f32x4;

#if defined(__has_builtin)
#  if __has_builtin(__builtin_amdgcn_exp2f)
#    define FAST_EXP2(x) __builtin_amdgcn_exp2f(x)
#  else
#    define FAST_EXP2(x) exp2f(x)
#  endif
#else
#  define FAST_EXP2(x) exp2f(x)
#endif

__device__ __forceinline__ short f2bf(float x) {
  __hip_bfloat16 h = __float2bfloat16(x);
  return *(short*)&h;
}

__device__ __forceinline__ bf16x8 cvt8(float4 lo, float4 hi) {
  bf16x8 r;
  r[0] = f2bf(lo.x); r[1] = f2bf(lo.y); r[2] = f2bf(lo.z); r[3] = f2bf(lo.w);
  r[4] = f2bf(hi.x); r[5] = f2bf(hi.y); r[6] = f2bf(hi.z); r[7] = f2bf(hi.w);
  return r;
}

// async 16B global->LDS copy: lds dest = wave-uniform base + lane*16.
__device__ __forceinline__ void dma16(const void* g, void* l) {
  __builtin_amdgcn_global_load_lds(
      (const __attribute__((address_space(1))) unsigned int*)g,
      (__attribute__((address_space(3))) unsigned int*)l, 16, 0, 0);
}

// ---------------------------------------------------------------------------
// Weight prep (all 3 heads): W1 (512x256)->w1t (256x512), W2 (256x128)->
// w2t (128x256), fp32 -> bf16, transposed so k is contiguous. grid (640, 3).
// ---------------------------------------------------------------------------
__global__ __launch_bounds__(256) void prep_w_kernel(
    const float* __restrict__ W1_0, const float* __restrict__ W1_1,
    const float* __restrict__ W1_2,
    const float* __restrict__ W2_0, const float* __restrict__ W2_1,
    const float* __restrict__ W2_2,
    ushort_t* __restrict__ w1t3, ushort_t* __restrict__ w2t3)
{
  const float* W1s[3] = {W1_0, W1_1, W1_2};
  const float* W2s[3] = {W2_0, W2_1, W2_2};
  const int z = blockIdx.y;
  int idx = blockIdx.x * 256 + threadIdx.x;
  if (idx < DHID * DIN) {
    int n = idx >> 9, k = idx & (DIN - 1);
    w1t3[(size_t)z * DHID * DIN + idx] = f2bf(W1s[z][(size_t)k * DHID + n]);
  } else {
    int j = idx - DHID * DIN;
    int n = j >> 8, k = j & (DHID - 1);
    w2t3[(size_t)z * DOUT * DHID + j] = f2bf(W2s[z][(size_t)k * DOUT + n]);
  }
}

// ---------------------------------------------------------------------------
// GEMM1 (all heads): H = relu(x @ W1 + b1). x fp32 loaded directly and
// converted in-register. Block 64x128 (waves 2x2, wave 32x64). K=512, 16 ki,
// ki-prefetched. grid (128, 2, 3).
// ---------------------------------------------------------------------------
__global__ __launch_bounds__(256) void gemm1_kernel(
    const float* __restrict__ x0, const float* __restrict__ x1,
    const float* __restrict__ x2,
    const ushort_t* __restrict__ w1t3,
    const float* __restrict__ b1_0, const float* __restrict__ b1_1,
    const float* __restrict__ b1_2,
    ushort_t* __restrict__ h3)
{
  const float* xs[3] = {x0, x1, x2};
  const float* bs[3] = {b1_0, b1_1, b1_2};
  const int z = blockIdx.z;
  const float* X = xs[z];
  const ushort_t* Bt = w1t3 + (size_t)z * DHID * DIN;
  ushort_t* H = h3 + (size_t)z * NROWS * DHID;

  const int tid = threadIdx.x, lane = tid & 63, wave = tid >> 6;
  const int wr = wave >> 1, wc = wave & 1, quad = lane >> 4, l16 = lane & 15;
  const int m0 = blockIdx.x * 64 + wr * 32;
  const int n0 = blockIdx.y * 128 + wc * 64;

  const float* px = X + (size_t)(m0 + l16) * DIN + quad * 8;
  const ushort_t* pb = Bt + (size_t)(n0 + l16) * DIN + quad * 8;

  f32x4 acc[2][4] = {};
  float4 af[2][2][2];
  bf16x8 b[2][4];
#pragma unroll
  for (int rt = 0; rt < 2; rt++) {
    af[0][rt][0] = *(const float4*)(px + rt * 16 * DIN);
    af[0][rt][1] = *(const float4*)(px + rt * 16 * DIN + 4);
  }
#pragma unroll
  for (int ct = 0; ct < 4; ct++) b[0][ct] = *(const bf16x8*)(pb + ct * 16 * DIN);

#pragma unroll
  for (int ki = 0; ki < 16; ki++) {
    const int cur = ki & 1;
    if (ki < 15) {
      const int off = (ki + 1) * 32;
#pragma unroll
      for (int rt = 0; rt < 2; rt++) {
        af[cur ^ 1][rt][0] = *(const float4*)(px + rt * 16 * DIN + off);
        af[cur ^ 1][rt][1] = *(const float4*)(px + rt * 16 * DIN + off + 4);
      }
#pragma unroll
      for (int ct = 0; ct < 4; ct++)
        b[cur ^ 1][ct] = *(const bf16x8*)(pb + ct * 16 * DIN + off);
    }
    bf16x8 a[2];
#pragma unroll
    for (int rt = 0; rt < 2; rt++) a[rt] = cvt8(af[cur][rt][0], af[cur][rt][1]);
#pragma unroll
    for (int rt = 0; rt < 2; rt++)
#pragma unroll
      for (int ct = 0; ct < 4; ct++)
        acc[rt][ct] = __builtin_amdgcn_mfma_f32_16x16x32_bf16(
            a[rt], b[cur][ct], acc[rt][ct], 0, 0, 0);
  }

  float bb[4];
#pragma unroll
  for (int ct = 0; ct < 4; ct++) bb[ct] = bs[z][n0 + ct * 16 + l16];
#pragma unroll
  for (int rt = 0; rt < 2; rt++)
#pragma unroll
    for (int ct = 0; ct < 4; ct++)
#pragma unroll
      for (int reg = 0; reg < 4; reg++) {
        float v = fmaxf(acc[rt][ct][reg] + bb[ct], 0.0f);
        H[(size_t)(m0 + rt * 16 + quad * 4 + reg) * DHID + n0 + ct * 16 + l16] =
            (ushort_t)f2bf(v);
      }
}

// ---------------------------------------------------------------------------
// GEMM2 (all heads): Y = H @ W2 + b2 (fp32) + column sum/sumsq atomics.
// Block 32x128 (waves 2x2, wave 16x64). K=256, 8 ki, prefetched.
// grid (256, 1, 3).
// ---------------------------------------------------------------------------
__global__ __launch_bounds__(256) void gemm2_kernel(
    const ushort_t* __restrict__ h3, const ushort_t* __restrict__ w2t3,
    const float* __restrict__ b2_0, const float* __restrict__ b2_1,
    const float* __restrict__ b2_2,
    float* __restrict__ y3,
    float* __restrict__ colsum, float* __restrict__ colsumsq)
{
  const float* bs[3] = {b2_0, b2_1, b2_2};
  const int z = blockIdx.z;
  const ushort_t* A = h3 + (size_t)z * NROWS * DHID;
  const ushort_t* Bt = w2t3 + (size_t)z * DOUT * DHID;
  float* Y = y3 + (size_t)z * NROWS * DOUT;
  float* csum = colsum + z * DOUT;
  float* csq  = colsumsq + z * DOUT;

  const int tid = threadIdx.x, lane = tid & 63, wave = tid >> 6;
  const int wr = wave >> 1, wc = wave & 1, quad = lane >> 4, l16 = lane & 15;
  const int m0 = blockIdx.x * 32 + wr * 16;
  const int n0 = wc * 64;

  const ushort_t* pa = A + (size_t)(m0 + l16) * DHID + quad * 8;
  const ushort_t* pb = Bt + (size_t)(n0 + l16) * DHID + quad * 8;

  f32x4 acc[4] = {};
  bf16x8 a[2], b[2][4];
  a[0] = *(const bf16x8*)pa;
#pragma unroll
  for (int ct = 0; ct < 4; ct++) b[0][ct] = *(const bf16x8*)(pb + ct * 16 * DHID);

#pragma unroll
  for (int ki = 0; ki < 8; ki++) {
    const int cur = ki & 1;
    if (ki < 7) {
      const int off = (ki + 1) * 32;
      a[cur ^ 1] = *(const bf16x8*)(pa + off);
#pragma unroll
      for (int ct = 0; ct < 4; ct++)
        b[cur ^ 1][ct] = *(const bf16x8*)(pb + ct * 16 * DHID + off);
    }
#pragma unroll
    for (int ct = 0; ct < 4; ct++)
      acc[ct] = __builtin_amdgcn_mfma_f32_16x16x32_bf16(
          a[cur], b[cur][ct], acc[ct], 0, 0, 0);
  }

  float bb[4];
#pragma unroll
  for (int ct = 0; ct < 4; ct++) bb[ct] = bs[z][n0 + ct * 16 + l16];
#pragma unroll
  for (int ct = 0; ct < 4; ct++) {
    float cs = 0.0f, cq = 0.0f;
#pragma unroll
    for (int reg = 0; reg < 4; reg++) {
      float v = acc[ct][reg] + bb[ct];
      Y[(size_t)(m0 + quad * 4 + reg) * DOUT + n0 + ct * 16 + l16] = v;
      cs += v; cq += v * v;
    }
    cs += __shfl_xor(cs, 16, 64); cs += __shfl_xor(cs, 32, 64);
    cq += __shfl_xor(cq, 16, 64); cq += __shfl_xor(cq, 32, 64);
    if (lane < 16) {
      atomicAdd(&csum[n0 + ct * 16 + l16], cs);
      atomicAdd(&csq[n0 + ct * 16 + l16], cq);
    }
  }
}

// ---------------------------------------------------------------------------
// Whitening stats finalize.
// ---------------------------------------------------------------------------
__global__ void stats_kernel(const float* __restrict__ colsum,
                             const float* __restrict__ colsumsq,
                             float* __restrict__ meanv, float* __restrict__ invsd)
{
  int i = threadIdx.x;
  if (i < 3 * DOUT) {
    float mu  = colsum[i] / (float)NROWS;
    float var = (colsumsq[i] - (float)NROWS * mu * mu) / (float)(NROWS - 1);
    float sd  = sqrtf(fmaxf(var, 0.0f)) + 1e-5f;
    meanv[i] = mu;
    invsd[i] = 1.0f / sd;
  }
}

// ---------------------------------------------------------------------------
// Whiten + L2-normalize + pos dots (fp32) + bf16 z (plain V + log2e-scaled U).
// ---------------------------------------------------------------------------
__global__ __launch_bounds__(128) void whiten_kernel(
    const float* __restrict__ y3,
    const float* __restrict__ meanv, const float* __restrict__ invsd,
    ushort_t* __restrict__ zB, ushort_t* __restrict__ zE,
    ushort_t* __restrict__ zF,
    ushort_t* __restrict__ zBs, ushort_t* __restrict__ zEs,
    float* __restrict__ pos)
{
  int row = blockIdx.x, t = threadIdx.x;
  size_t off = (size_t)row * DOUT + t;
  const size_t hs = (size_t)NROWS * DOUT;
  float vB = (y3[off]          - meanv[t])            * invsd[t];
  float vE = (y3[off + hs]     - meanv[DOUT + t])     * invsd[DOUT + t];
  float vF = (y3[off + 2 * hs] - meanv[2 * DOUT + t]) * invsd[2 * DOUT + t];

  __shared__ float red[6], red2[6];
  float nB = vB * vB, nE = vE * vE, nF = vF * vF;
#pragma unroll
  for (int o = 32; o > 0; o >>= 1) {
    nB += __shfl_down(nB, o, 64);
    nE += __shfl_down(nE, o, 64);
    nF += __shfl_down(nF, o, 64);
  }
  int lane = t & 63, wv = t >> 6;
  if (lane == 0) { red[wv * 3] = nB; red[wv * 3 + 1] = nE; red[wv * 3 + 2] = nF; }
  __syncthreads();
  float iB = 1.0f / fmaxf(sqrtf(red[0] + red[3]), 1e-12f);
  float iE = 1.0f / fmaxf(sqrtf(red[1] + red[4]), 1e-12f);
  float iF = 1.0f / fmaxf(sqrtf(red[2] + red[5]), 1e-12f);
  float zb = vB * iB, ze = vE * iE, zf = vF * iF;

  zB[off]  = (ushort_t)f2bf(zb);
  zE[off]  = (ushort_t)f2bf(ze);
  zF[off]  = (ushort_t)f2bf(zf);
  zBs[off] = (ushort_t)f2bf(zb * LOG2E);
  zEs[off] = (ushort_t)f2bf(ze * LOG2E);

  float pBE = zb * ze, pBF = zb * zf, pEF = ze * zf;
#pragma unroll
  for (int o = 32; o > 0; o >>= 1) {
    pBE += __shfl_down(pBE, o, 64);
    pBF += __shfl_down(pBF, o, 64);
    pEF += __shfl_down(pEF, o, 64);
  }
  if (lane == 0) { red2[wv * 3] = pBE; red2[wv * 3 + 1] = pBF; red2[wv * 3 + 2] = pEF; }
  __syncthreads();
  if (t == 0) {
    pos[row]             = red2[0] + red2[3];
    pos[NROWS + row]     = red2[1] + red2[4];
    pos[2 * NROWS + row] = red2[2] + red2[5];
  }
}

// ---------------------------------------------------------------------------
// Gram v6: rowsum_i += sum_j exp2(Us_i . V_j), 5 combos. m97-style async
// staging: V-chunks (32 cols x 128 k = 8 KB) DMA'd via global_load_lds into
// a double-buffered LDS tile; 4 waves stacked in m (256 rows) share it.
// A-frags in regs (64 VGPR). LDS layout [k-seg s=ki*4+quad][col r]*16B so
// ds_read_b128 start banks stride by 4. One __syncthreads per chunk; DMA
// for c+1 issued before chunk c's compute. grid (32, 16, 5).
// ---------------------------------------------------------------------------
#define G_CH  32                    // cols per chunk
#define G_NCH 16                    // chunks per block (512 cols)
__global__ __launch_bounds__(256, 3) void gram_kernel(
    const ushort_t* __restrict__ zB, const ushort_t* __restrict__ zE,
    const ushort_t* __restrict__ zF,
    const ushort_t* __restrict__ zBs, const ushort_t* __restrict__ zEs,
    float* __restrict__ rowsum)
{
  const ushort_t *U, *V;
  float* rs;
  switch (blockIdx.z) {
    case 0:  U = zBs; V = zB; rs = rowsum;             break;
    case 1:  U = zEs; V = zE; rs = rowsum + NROWS;     break;
    case 2:  U = zBs; V = zE; rs = rowsum + 2 * NROWS; break;
    case 3:  U = zBs; V = zF; rs = rowsum + 3 * NROWS; break;
    default: U = zEs; V = zF; rs = rowsum + 4 * NROWS; break;
  }

  const int tid = threadIdx.x, lane = tid & 63, wave = tid >> 6;
  const int quad = lane >> 4, l16 = lane & 15;
  const int m0 = blockIdx.x * 256 + wave * 64;      // waves stacked in m
  const int col0 = blockIdx.y * (G_CH * G_NCH);

  __shared__ __align__(16) ushort_t sbuf[2][4096];  // 2 x 8 KB

  // cache this wave's A fragments: 64 rows x 128 k (16 frags = 64 VGPR)
  const ushort_t* ua = U + (size_t)(m0 + l16) * DOUT + quad * 8;
  bf16x8 a[4][4];
#pragma unroll
  for (int rt = 0; rt < 4; rt++)
#pragma unroll
    for (int ki = 0; ki < 4; ki++)
      a[rt][ki] = *(const bf16x8*)(ua + rt * 16 * DOUT + ki * 32);

  // DMA source pointers: wave w issues insts j=2w,2w+1. Lane i of inst j
  // fetches global (col = col0 + c*32 + (i&31), k-seg s = 2j + (i>>5)),
  // landing at LDS byte j*1024 + i*16 = seg s*512 + (i&31)*16.
  const char* Vb = (const char*)V;
  const int r_ = lane & 31, hi_ = lane >> 5;
  const int s0 = 4 * wave + hi_, s1 = 4 * wave + 2 + hi_;
  const char* g0 = Vb + (size_t)(col0 + r_) * 256 + (s0 >> 2) * 64 + (s0 & 3) * 16;
  const char* g1 = Vb + (size_t)(col0 + r_) * 256 + (s1 >> 2) * 64 + (s1 & 3) * 16;

  float rsum[4][4] = {};
  const f32x4 zero = {0.0f, 0.0f, 0.0f, 0.0f};

  // prime chunk 0
  dma16(g0, &sbuf[0][(2 * wave) * 512]);
  dma16(g1, &sbuf[0][(2 * wave + 1) * 512]);
  __syncthreads();

  for (int c = 0; c < G_NCH; c++) {
    const int buf = c & 1;
    if (c + 1 < G_NCH) {
      const size_t go = (size_t)(c + 1) * 8192;
      dma16(g0 + go, &sbuf[buf ^ 1][(2 * wave) * 512]);
      dma16(g1 + go, &sbuf[buf ^ 1][(2 * wave + 1) * 512]);
    }
    // read this wave's b-fragments from LDS: (ki, ct) -> seg ki*4+quad,
    // col ct*16+l16
    const char* sb = (const char*)&sbuf[buf][0];
    bf16x8 b[4][2];
#pragma unroll
    for (int ki = 0; ki < 4; ki++)
#pragma unroll
      for (int ct = 0; ct < 2; ct++)
        b[ki][ct] = *(const bf16x8*)(sb + (ki * 4 + quad) * 512 +
                                     (ct * 16 + l16) * 16);
    f32x4 acc[4][2];
#pragma unroll
    for (int ki = 0; ki < 4; ki++)
#pragma unroll
      for (int rt = 0; rt < 4; rt++)
#pragma unroll
        for (int ct = 0; ct < 2; ct++)
          acc[rt][ct] = __builtin_amdgcn_mfma_f32_16x16x32_bf16(
              a[rt][ki], b[ki][ct], ki == 0 ? zero : acc[rt][ct], 0, 0, 0);
    // exp2 + in-register row accumulation
#pragma unroll
    for (int rt = 0; rt < 4; rt++)
#pragma unroll
      for (int reg = 0; reg < 4; reg++)
        rsum[rt][reg] += FAST_EXP2(acc[rt][0][reg]) + FAST_EXP2(acc[rt][1][reg]);
    __syncthreads();
  }

  // one cross-lane reduction over l16 + one atomic per row per block
#pragma unroll
  for (int rt = 0; rt < 4; rt++)
#pragma unroll
    for (int reg = 0; reg < 4; reg++) {
      float s = rsum[rt][reg];
      s += __shfl_xor(s, 1, 64);
      s += __shfl_xor(s, 2, 64);
      s += __shfl_xor(s, 4, 64);
      s += __shfl_xor(s, 8, 64);
      if (l16 == 0)
        atomicAdd(&rs[m0 + rt * 16 + quad * 4 + reg], s);
    }
}

// ---------------------------------------------------------------------------
// Final loss. logits[i,i] masked to 0: self + (1 - e).
// ---------------------------------------------------------------------------
__global__ __launch_bounds__(1024) void loss_kernel(
    const float* __restrict__ rowsum, const float* __restrict__ pos,
    float* __restrict__ out)
{
  const float* sB  = rowsum;
  const float* sE  = rowsum + NROWS;
  const float* cBE = rowsum + 2 * NROWS;
  const float* cBF = rowsum + 3 * NROWS;
  const float* cEF = rowsum + 4 * NROWS;
  const float* pBE = pos;
  const float* pBF = pos + NROWS;
  const float* pEF = pos + 2 * NROWS;

  const float corr = 1.0f - expf(1.0f);
  float local = 0.0f;
  for (int i = threadIdx.x; i < NROWS; i += 1024) {
    float selB = sB[i] + corr;
    float selE = sE[i] + corr;
    local += __logf(selB + cBE[i]) - pBE[i];
    local += __logf(selB + cBF[i]) - pBF[i];
    local += __logf(selE + cEF[i]) - pEF[i];
  }
  __shared__ float red[16];
#pragma unroll
  for (int o = 32; o > 0; o >>= 1) local += __shfl_down(local, o, 64);
  int lane = threadIdx.x & 63, wv = threadIdx.x >> 6;
  if (lane == 0) red[wv] = local;
  __syncthreads();
  if (threadIdx.x == 0) {
    float t = 0.0f;
#pragma unroll
    for (int w = 0; w < 16; w++) t += red[w];
    out[0] = t / (3.0f * (float)NROWS);
  }
}

// ---------------------------------------------------------------------------
extern "C" void kernel_launch(void* const* d_in, const int* in_sizes, int n_in,
                              void* d_out, int out_size, void* d_ws, size_t ws_size,
                              hipStream_t stream)
{
  const float* xs[3] = {(const float*)d_in[0], (const float*)d_in[1], (const float*)d_in[2]};
  const float* W1[3] = {(const float*)d_in[3], (const float*)d_in[7],  (const float*)d_in[11]};
  const float* b1[3] = {(const float*)d_in[4], (const float*)d_in[8],  (const float*)d_in[12]};
  const float* W2[3] = {(const float*)d_in[5], (const float*)d_in[9],  (const float*)d_in[13]};
  const float* b2[3] = {(const float*)d_in[6], (const float*)d_in[10], (const float*)d_in[14]};

  float* ws = (float*)d_ws;
  // workspace layout (float offsets):
  float* colsum   = ws;            // 384   [zeroed]
  float* colsumsq = ws + 384;      // 384   [zeroed]
  float* rowsum   = ws + 768;      // 5*8192 [zeroed]
  float* meanv    = ws + 41728;    // 384
  float* invsd    = ws + 42112;    // 384
  float* pos      = ws + 42496;    // 3*8192 -> ends 67072
  ushort_t* w1t3 = (ushort_t*)(ws + 67072);    // 3*256*512 bf16 = 196608 fl
  ushort_t* w2t3 = (ushort_t*)(ws + 263680);   // 3*128*256 bf16 = 49152 fl
  ushort_t* h3   = (ushort_t*)(ws + 312832);   // 3*8192*256 bf16 = 3145728 fl
  float*    y3   = ws + 3458560;               // 3*8192*128 fp32 = 3145728 fl
  // z buffers overlay h3 (dead after gemm2): 5 x 8192*128 bf16
  ushort_t* zB  = (ushort_t*)(ws + 312832);
  ushort_t* zE  = zB  + (size_t)NROWS * DOUT;
  ushort_t* zF  = zE  + (size_t)NROWS * DOUT;
  ushort_t* zBs = zF  + (size_t)NROWS * DOUT;
  ushort_t* zEs = zBs + (size_t)NROWS * DOUT;
  // peak ws usage: 6,604,288 floats = 26.4 MB

  hipMemsetAsync(ws, 0, 41728 * sizeof(float), stream);

  prep_w_kernel<<<dim3(640, 3), 256, 0, stream>>>(
      W1[0], W1[1], W1[2], W2[0], W2[1], W2[2], w1t3, w2t3);
  gemm1_kernel<<<dim3(128, 2, 3), 256, 0, stream>>>(
      xs[0], xs[1], xs[2], w1t3, b1[0], b1[1], b1[2], h3);
  gemm2_kernel<<<dim3(256, 1, 3), 256, 0, stream>>>(
      h3, w2t3, b2[0], b2[1], b2[2], y3, colsum, colsumsq);
  stats_kernel<<<1, 3 * DOUT, 0, stream>>>(colsum, colsumsq, meanv, invsd);
  whiten_kernel<<<NROWS, 128, 0, stream>>>(
      y3, meanv, invsd, zB, zE, zF, zBs, zEs, pos);
  gram_kernel<<<dim3(32, 16, 5), 256, 0, stream>>>(zB, zE, zF, zBs, zEs, rowsum);
  loss_kernel<<<1, 1024, 0, stream>>>(rowsum, pos, (float*)d_out);
}

// Round 7
// 283.528 us; speedup vs baseline: 1.5034x; 1.0471x over previous
//
#include <hip/hip_runtime.h>
#include <hip/hip_bf16.h>
#include <math.h>

#define NROWS 8192
#define DIN   512
#define DHID  256
#define DOUT  128
#define LOG2E 1.4426950408889634f

typedef unsigned short ushort_t;
typedef __attribute__((ext_vector_type(8))) short bf16x8;
typedef __attribute__((ext_vector_type(4))) float f32x4;

#if defined(__has_builtin)
#  if __has_builtin(__builtin_amdgcn_exp2f)
#    define FAST_EXP2(x) __builtin_amdgcn_exp2f(x)
#  else
#    define FAST_EXP2(x) exp2f(x)
#  endif
#else
#  define FAST_EXP2(x) exp2f(x)
#endif

__device__ __forceinline__ short f2bf(float x) {
  __hip_bfloat16 h = __float2bfloat16(x);
  return *(short*)&h;
}

__device__ __forceinline__ bf16x8 cvt8(float4 lo, float4 hi) {
  bf16x8 r;
  r[0] = f2bf(lo.x); r[1] = f2bf(lo.y); r[2] = f2bf(lo.z); r[3] = f2bf(lo.w);
  r[4] = f2bf(hi.x); r[5] = f2bf(hi.y); r[6] = f2bf(hi.z); r[7] = f2bf(hi.w);
  return r;
}

// async 16B global->LDS copy: lds dest = wave-uniform base + lane*16.
__device__ __forceinline__ void dma16(const void* g, void* l) {
  __builtin_amdgcn_global_load_lds(
      (const __attribute__((address_space(1))) unsigned int*)g,
      (__attribute__((address_space(3))) unsigned int*)l, 16, 0, 0);
}

// ---------------------------------------------------------------------------
// Weight prep (all 3 heads): W1 (512x256)->w1t (256x512), W2 (256x128)->
// w2t (128x256), fp32 -> bf16, transposed so k is contiguous. grid (640, 3).
// ---------------------------------------------------------------------------
__global__ __launch_bounds__(256) void prep_w_kernel(
    const float* __restrict__ W1_0, const float* __restrict__ W1_1,
    const float* __restrict__ W1_2,
    const float* __restrict__ W2_0, const float* __restrict__ W2_1,
    const float* __restrict__ W2_2,
    ushort_t* __restrict__ w1t3, ushort_t* __restrict__ w2t3)
{
  const float* W1s[3] = {W1_0, W1_1, W1_2};
  const float* W2s[3] = {W2_0, W2_1, W2_2};
  const int z = blockIdx.y;
  int idx = blockIdx.x * 256 + threadIdx.x;
  if (idx < DHID * DIN) {
    int n = idx >> 9, k = idx & (DIN - 1);
    w1t3[(size_t)z * DHID * DIN + idx] = f2bf(W1s[z][(size_t)k * DHID + n]);
  } else {
    int j = idx - DHID * DIN;
    int n = j >> 8, k = j & (DHID - 1);
    w2t3[(size_t)z * DOUT * DHID + j] = f2bf(W2s[z][(size_t)k * DOUT + n]);
  }
}

// ---------------------------------------------------------------------------
// Fused MLP (all heads): y = (relu(x@W1+b1))@W2 + b2, fp32 out + col stats.
// Block = 32 rows, 4 waves: phase1 wave (mw=w&1, nh=w>>1) computes
// 16 rows x 128 cols of h (K=512, x fp32 cvt in-reg, b dbuf), relu -> LDS
// h-tile (stride 264 bf16: 2-way max bank aliasing = free). One barrier.
// Phase2: same wave split over 128 out cols (ds_read_b128 A-frags, K=256).
// grid (256, 3) = 768 blocks = 3/CU exact.
// ---------------------------------------------------------------------------
__global__ __launch_bounds__(256, 3) void mlp_kernel(
    const float* __restrict__ x0, const float* __restrict__ x1,
    const float* __restrict__ x2,
    const ushort_t* __restrict__ w1t3,
    const float* __restrict__ b1_0, const float* __restrict__ b1_1,
    const float* __restrict__ b1_2,
    const ushort_t* __restrict__ w2t3,
    const float* __restrict__ b2_0, const float* __restrict__ b2_1,
    const float* __restrict__ b2_2,
    float* __restrict__ y3,
    float* __restrict__ colsum, float* __restrict__ colsumsq)
{
  const float* xs[3]  = {x0, x1, x2};
  const float* b1s[3] = {b1_0, b1_1, b1_2};
  const float* b2s[3] = {b2_0, b2_1, b2_2};
  const int z = blockIdx.y;
  const float* X = xs[z];
  const ushort_t* W1t = w1t3 + (size_t)z * DHID * DIN;
  const ushort_t* W2t = w2t3 + (size_t)z * DOUT * DHID;
  float* Y    = y3 + (size_t)z * NROWS * DOUT;
  float* csum = colsum + z * DOUT;
  float* csq  = colsumsq + z * DOUT;

  __shared__ __align__(16) ushort_t hs[32][264];  // +8 pad: 2-way banks max

  const int tid = threadIdx.x, lane = tid & 63, wave = tid >> 6;
  const int mw = wave & 1, nh = wave >> 1;
  const int quad = lane >> 4, l16 = lane & 15;
  const int m0 = blockIdx.x * 32;

  // ---- phase 1: h[mw*16..+16][nh*128..+128] = relu(x @ W1 + b1)
  const float* px = X + (size_t)(m0 + mw * 16 + l16) * DIN + quad * 8;
  const ushort_t* pb = W1t + (size_t)(nh * 128 + l16) * DIN + quad * 8;

  f32x4 acc1[8] = {};
  float4 af[2][2];
  bf16x8 b[2][8];
  af[0][0] = *(const float4*)px;
  af[0][1] = *(const float4*)(px + 4);
#pragma unroll
  for (int ct = 0; ct < 8; ct++) b[0][ct] = *(const bf16x8*)(pb + ct * 16 * DIN);

#pragma unroll
  for (int ki = 0; ki < 16; ki++) {
    const int cur = ki & 1;
    if (ki < 15) {
      const int off = (ki + 1) * 32;
      af[cur ^ 1][0] = *(const float4*)(px + off);
      af[cur ^ 1][1] = *(const float4*)(px + off + 4);
#pragma unroll
      for (int ct = 0; ct < 8; ct++)
        b[cur ^ 1][ct] = *(const bf16x8*)(pb + ct * 16 * DIN + off);
    }
    bf16x8 a = cvt8(af[cur][0], af[cur][1]);
#pragma unroll
    for (int ct = 0; ct < 8; ct++)
      acc1[ct] = __builtin_amdgcn_mfma_f32_16x16x32_bf16(a, b[cur][ct],
                                                         acc1[ct], 0, 0, 0);
  }
  // epilogue 1: bias + relu + bf16 -> LDS (C: row=quad*4+reg, col=ct*16+l16)
#pragma unroll
  for (int ct = 0; ct < 8; ct++) {
    float bb = b1s[z][nh * 128 + ct * 16 + l16];
#pragma unroll
    for (int reg = 0; reg < 4; reg++) {
      float v = fmaxf(acc1[ct][reg] + bb, 0.0f);
      hs[mw * 16 + quad * 4 + reg][nh * 128 + ct * 16 + l16] = (ushort_t)f2bf(v);
    }
  }
  __syncthreads();

  // ---- phase 2: y[16 rows][nh*64..+64] = h @ W2 + b2
  const ushort_t* pb2 = W2t + (size_t)(nh * 64 + l16) * DHID + quad * 8;
  f32x4 acc2[4] = {};
  bf16x8 a2[2], b2f[2][4];
  a2[0] = *(const bf16x8*)&hs[mw * 16 + l16][quad * 8];
#pragma unroll
  for (int ct = 0; ct < 4; ct++) b2f[0][ct] = *(const bf16x8*)(pb2 + ct * 16 * DHID);

#pragma unroll
  for (int ki = 0; ki < 8; ki++) {
    const int cur = ki & 1;
    if (ki < 7) {
      const int off = (ki + 1) * 32;
      a2[cur ^ 1] = *(const bf16x8*)&hs[mw * 16 + l16][off + quad * 8];
#pragma unroll
      for (int ct = 0; ct < 4; ct++)
        b2f[cur ^ 1][ct] = *(const bf16x8*)(pb2 + ct * 16 * DHID + off);
    }
#pragma unroll
    for (int ct = 0; ct < 4; ct++)
      acc2[ct] = __builtin_amdgcn_mfma_f32_16x16x32_bf16(a2[cur], b2f[cur][ct],
                                                         acc2[ct], 0, 0, 0);
  }
  // epilogue 2: bias, store y, column sum/sumsq atomics
#pragma unroll
  for (int ct = 0; ct < 4; ct++) {
    float bb = b2s[z][nh * 64 + ct * 16 + l16];
    float cs = 0.0f, cq = 0.0f;
#pragma unroll
    for (int reg = 0; reg < 4; reg++) {
      float v = acc2[ct][reg] + bb;
      Y[(size_t)(m0 + mw * 16 + quad * 4 + reg) * DOUT + nh * 64 + ct * 16 + l16] = v;
      cs += v; cq += v * v;
    }
    cs += __shfl_xor(cs, 16, 64); cs += __shfl_xor(cs, 32, 64);
    cq += __shfl_xor(cq, 16, 64); cq += __shfl_xor(cq, 32, 64);
    if (lane < 16) {
      atomicAdd(&csum[nh * 64 + ct * 16 + l16], cs);
      atomicAdd(&csq[nh * 64 + ct * 16 + l16], cq);
    }
  }
}

// ---------------------------------------------------------------------------
// Whitening stats finalize.
// ---------------------------------------------------------------------------
__global__ void stats_kernel(const float* __restrict__ colsum,
                             const float* __restrict__ colsumsq,
                             float* __restrict__ meanv, float* __restrict__ invsd)
{
  int i = threadIdx.x;
  if (i < 3 * DOUT) {
    float mu  = colsum[i] / (float)NROWS;
    float var = (colsumsq[i] - (float)NROWS * mu * mu) / (float)(NROWS - 1);
    float sd  = sqrtf(fmaxf(var, 0.0f)) + 1e-5f;
    meanv[i] = mu;
    invsd[i] = 1.0f / sd;
  }
}

// ---------------------------------------------------------------------------
// Whiten + L2-normalize + pos dots (fp32) + bf16 z (plain V + log2e-scaled U).
// ---------------------------------------------------------------------------
__global__ __launch_bounds__(128) void whiten_kernel(
    const float* __restrict__ y3,
    const float* __restrict__ meanv, const float* __restrict__ invsd,
    ushort_t* __restrict__ zB, ushort_t* __restrict__ zE,
    ushort_t* __restrict__ zF,
    ushort_t* __restrict__ zBs, ushort_t* __restrict__ zEs,
    float* __restrict__ pos)
{
  int row = blockIdx.x, t = threadIdx.x;
  size_t off = (size_t)row * DOUT + t;
  const size_t hs = (size_t)NROWS * DOUT;
  float vB = (y3[off]          - meanv[t])            * invsd[t];
  float vE = (y3[off + hs]     - meanv[DOUT + t])     * invsd[DOUT + t];
  float vF = (y3[off + 2 * hs] - meanv[2 * DOUT + t]) * invsd[2 * DOUT + t];

  __shared__ float red[6], red2[6];
  float nB = vB * vB, nE = vE * vE, nF = vF * vF;
#pragma unroll
  for (int o = 32; o > 0; o >>= 1) {
    nB += __shfl_down(nB, o, 64);
    nE += __shfl_down(nE, o, 64);
    nF += __shfl_down(nF, o, 64);
  }
  int lane = t & 63, wv = t >> 6;
  if (lane == 0) { red[wv * 3] = nB; red[wv * 3 + 1] = nE; red[wv * 3 + 2] = nF; }
  __syncthreads();
  float iB = 1.0f / fmaxf(sqrtf(red[0] + red[3]), 1e-12f);
  float iE = 1.0f / fmaxf(sqrtf(red[1] + red[4]), 1e-12f);
  float iF = 1.0f / fmaxf(sqrtf(red[2] + red[5]), 1e-12f);
  float zb = vB * iB, ze = vE * iE, zf = vF * iF;

  zB[off]  = (ushort_t)f2bf(zb);
  zE[off]  = (ushort_t)f2bf(ze);
  zF[off]  = (ushort_t)f2bf(zf);
  zBs[off] = (ushort_t)f2bf(zb * LOG2E);
  zEs[off] = (ushort_t)f2bf(ze * LOG2E);

  float pBE = zb * ze, pBF = zb * zf, pEF = ze * zf;
#pragma unroll
  for (int o = 32; o > 0; o >>= 1) {
    pBE += __shfl_down(pBE, o, 64);
    pBF += __shfl_down(pBF, o, 64);
    pEF += __shfl_down(pEF, o, 64);
  }
  if (lane == 0) { red2[wv * 3] = pBE; red2[wv * 3 + 1] = pBF; red2[wv * 3 + 2] = pEF; }
  __syncthreads();
  if (t == 0) {
    pos[row]             = red2[0] + red2[3];
    pos[NROWS + row]     = red2[1] + red2[4];
    pos[2 * NROWS + row] = red2[2] + red2[5];
  }
}

// ---------------------------------------------------------------------------
// Gram v7: rowsum_i += sum_j exp2(Us_i . V_j), 5 combos. Async LDS staging
// (v6 structure) with G_NCH=32 chunks and grid (32, 8, 5) = 1280 blocks =
// exactly 5/CU residency (no tail round); a-frag setup + atomics amortized.
// ---------------------------------------------------------------------------
#define G_CH  32                    // cols per chunk
#define G_NCH 32                    // chunks per block (1024 cols)
__global__ __launch_bounds__(256, 3) void gram_kernel(
    const ushort_t* __restrict__ zB, const ushort_t* __restrict__ zE,
    const ushort_t* __restrict__ zF,
    const ushort_t* __restrict__ zBs, const ushort_t* __restrict__ zEs,
    float* __restrict__ rowsum)
{
  const ushort_t *U, *V;
  float* rs;
  switch (blockIdx.z) {
    case 0:  U = zBs; V = zB; rs = rowsum;             break;
    case 1:  U = zEs; V = zE; rs = rowsum + NROWS;     break;
    case 2:  U = zBs; V = zE; rs = rowsum + 2 * NROWS; break;
    case 3:  U = zBs; V = zF; rs = rowsum + 3 * NROWS; break;
    default: U = zEs; V = zF; rs = rowsum + 4 * NROWS; break;
  }

  const int tid = threadIdx.x, lane = tid & 63, wave = tid >> 6;
  const int quad = lane >> 4, l16 = lane & 15;
  const int m0 = blockIdx.x * 256 + wave * 64;      // waves stacked in m
  const int col0 = blockIdx.y * (G_CH * G_NCH);

  __shared__ __align__(16) ushort_t sbuf[2][4096];  // 2 x 8 KB

  // cache this wave's A fragments: 64 rows x 128 k (16 frags = 64 VGPR)
  const ushort_t* ua = U + (size_t)(m0 + l16) * DOUT + quad * 8;
  bf16x8 a[4][4];
#pragma unroll
  for (int rt = 0; rt < 4; rt++)
#pragma unroll
    for (int ki = 0; ki < 4; ki++)
      a[rt][ki] = *(const bf16x8*)(ua + rt * 16 * DOUT + ki * 32);

  // DMA source pointers: wave w issues insts j=2w,2w+1. Lane i of inst j
  // fetches global (col = col0 + c*32 + (i&31), k-seg s = 2j + (i>>5)),
  // landing at LDS byte j*1024 + i*16 = seg s*512 + (i&31)*16.
  const char* Vb = (const char*)V;
  const int r_ = lane & 31, hi_ = lane >> 5;
  const int s0 = 4 * wave + hi_, s1 = 4 * wave + 2 + hi_;
  const char* g0 = Vb + (size_t)(col0 + r_) * 256 + (s0 >> 2) * 64 + (s0 & 3) * 16;
  const char* g1 = Vb + (size_t)(col0 + r_) * 256 + (s1 >> 2) * 64 + (s1 & 3) * 16;

  float rsum[4][4] = {};
  const f32x4 zero = {0.0f, 0.0f, 0.0f, 0.0f};

  // prime chunk 0
  dma16(g0, &sbuf[0][(2 * wave) * 512]);
  dma16(g1, &sbuf[0][(2 * wave + 1) * 512]);
  __syncthreads();

  for (int c = 0; c < G_NCH; c++) {
    const int buf = c & 1;
    if (c + 1 < G_NCH) {
      const size_t go = (size_t)(c + 1) * 8192;
      dma16(g0 + go, &sbuf[buf ^ 1][(2 * wave) * 512]);
      dma16(g1 + go, &sbuf[buf ^ 1][(2 * wave + 1) * 512]);
    }
    // read this wave's b-fragments from LDS: (ki, ct) -> seg ki*4+quad,
    // col ct*16+l16
    const char* sb = (const char*)&sbuf[buf][0];
    bf16x8 b[4][2];
#pragma unroll
    for (int ki = 0; ki < 4; ki++)
#pragma unroll
      for (int ct = 0; ct < 2; ct++)
        b[ki][ct] = *(const bf16x8*)(sb + (ki * 4 + quad) * 512 +
                                     (ct * 16 + l16) * 16);
    f32x4 acc[4][2];
#pragma unroll
    for (int ki = 0; ki < 4; ki++)
#pragma unroll
      for (int rt = 0; rt < 4; rt++)
#pragma unroll
        for (int ct = 0; ct < 2; ct++)
          acc[rt][ct] = __builtin_amdgcn_mfma_f32_16x16x32_bf16(
              a[rt][ki], b[ki][ct], ki == 0 ? zero : acc[rt][ct], 0, 0, 0);
    // exp2 + in-register row accumulation
#pragma unroll
    for (int rt = 0; rt < 4; rt++)
#pragma unroll
      for (int reg = 0; reg < 4; reg++)
        rsum[rt][reg] += FAST_EXP2(acc[rt][0][reg]) + FAST_EXP2(acc[rt][1][reg]);
    __syncthreads();
  }

  // one cross-lane reduction over l16 + one atomic per row per block
#pragma unroll
  for (int rt = 0; rt < 4; rt++)
#pragma unroll
    for (int reg = 0; reg < 4; reg++) {
      float s = rsum[rt][reg];
      s += __shfl_xor(s, 1, 64);
      s += __shfl_xor(s, 2, 64);
      s += __shfl_xor(s, 4, 64);
      s += __shfl_xor(s, 8, 64);
      if (l16 == 0)
        atomicAdd(&rs[m0 + rt * 16 + quad * 4 + reg], s);
    }
}

// ---------------------------------------------------------------------------
// Final loss. logits[i,i] masked to 0: self + (1 - e).
// ---------------------------------------------------------------------------
__global__ __launch_bounds__(1024) void loss_kernel(
    const float* __restrict__ rowsum, const float* __restrict__ pos,
    float* __restrict__ out)
{
  const float* sB  = rowsum;
  const float* sE  = rowsum + NROWS;
  const float* cBE = rowsum + 2 * NROWS;
  const float* cBF = rowsum + 3 * NROWS;
  const float* cEF = rowsum + 4 * NROWS;
  const float* pBE = pos;
  const float* pBF = pos + NROWS;
  const float* pEF = pos + 2 * NROWS;

  const float corr = 1.0f - expf(1.0f);
  float local = 0.0f;
  for (int i = threadIdx.x; i < NROWS; i += 1024) {
    float selB = sB[i] + corr;
    float selE = sE[i] + corr;
    local += __logf(selB + cBE[i]) - pBE[i];
    local += __logf(selB + cBF[i]) - pBF[i];
    local += __logf(selE + cEF[i]) - pEF[i];
  }
  __shared__ float red[16];
#pragma unroll
  for (int o = 32; o > 0; o >>= 1) local += __shfl_down(local, o, 64);
  int lane = threadIdx.x & 63, wv = threadIdx.x >> 6;
  if (lane == 0) red[wv] = local;
  __syncthreads();
  if (threadIdx.x == 0) {
    float t = 0.0f;
#pragma unroll
    for (int w = 0; w < 16; w++) t += red[w];
    out[0] = t / (3.0f * (float)NROWS);
  }
}

// ---------------------------------------------------------------------------
extern "C" void kernel_launch(void* const* d_in, const int* in_sizes, int n_in,
                              void* d_out, int out_size, void* d_ws, size_t ws_size,
                              hipStream_t stream)
{
  const float* xs[3] = {(const float*)d_in[0], (const float*)d_in[1], (const float*)d_in[2]};
  const float* W1[3] = {(const float*)d_in[3], (const float*)d_in[7],  (const float*)d_in[11]};
  const float* b1[3] = {(const float*)d_in[4], (const float*)d_in[8],  (const float*)d_in[12]};
  const float* W2[3] = {(const float*)d_in[5], (const float*)d_in[9],  (const float*)d_in[13]};
  const float* b2[3] = {(const float*)d_in[6], (const float*)d_in[10], (const float*)d_in[14]};

  float* ws = (float*)d_ws;
  // workspace layout (float offsets):
  float* colsum   = ws;            // 384   [zeroed]
  float* colsumsq = ws + 384;      // 384   [zeroed]
  float* rowsum   = ws + 768;      // 5*8192 [zeroed]
  float* meanv    = ws + 41728;    // 384
  float* invsd    = ws + 42112;    // 384
  float* pos      = ws + 42496;    // 3*8192 -> ends 67072
  ushort_t* w1t3 = (ushort_t*)(ws + 67072);    // 3*256*512 bf16 = 196608 fl
  ushort_t* w2t3 = (ushort_t*)(ws + 263680);   // 3*128*256 bf16 = 49152 fl
  float*    y3   = ws + 312832;                // 3*8192*128 fp32 = 3145728 fl
  ushort_t* zB   = (ushort_t*)(ws + 3458560);  // 5 x 8192*128 bf16
  ushort_t* zE   = zB  + (size_t)NROWS * DOUT;
  ushort_t* zF   = zE  + (size_t)NROWS * DOUT;
  ushort_t* zBs  = zF  + (size_t)NROWS * DOUT;
  ushort_t* zEs  = zBs + (size_t)NROWS * DOUT;
  // peak ws usage: 6,080,000 floats = 24.3 MB

  hipMemsetAsync(ws, 0, 41728 * sizeof(float), stream);

  prep_w_kernel<<<dim3(640, 3), 256, 0, stream>>>(
      W1[0], W1[1], W1[2], W2[0], W2[1], W2[2], w1t3, w2t3);
  mlp_kernel<<<dim3(256, 3), 256, 0, stream>>>(
      xs[0], xs[1], xs[2], w1t3, b1[0], b1[1], b1[2],
      w2t3, b2[0], b2[1], b2[2], y3, colsum, colsumsq);
  stats_kernel<<<1, 3 * DOUT, 0, stream>>>(colsum, colsumsq, meanv, invsd);
  whiten_kernel<<<NROWS, 128, 0, stream>>>(
      y3, meanv, invsd, zB, zE, zF, zBs, zEs, pos);
  gram_kernel<<<dim3(32, 8, 5), 256, 0, stream>>>(zB, zE, zF, zBs, zEs, rowsum);
  loss_kernel<<<1, 1024, 0, stream>>>(rowsum, pos, (float*)d_out);
}

// Round 8
// 236.971 us; speedup vs baseline: 1.7988x; 1.1965x over previous
//
#include <hip/hip_runtime.h>
#include <hip/hip_bf16.h>
#include <math.h>

#define NROWS 8192
#define DIN   512
#define DHID  256
#define DOUT  128
#define LOG2E 1.4426950408889634f

typedef unsigned short ushort_t;
typedef __attribute__((ext_vector_type(8))) short bf16x8;
typedef __attribute__((ext_vector_type(4))) float f32x4;

#if defined(__has_builtin)
#  if __has_builtin(__builtin_amdgcn_exp2f)
#    define FAST_EXP2(x) __builtin_amdgcn_exp2f(x)
#  else
#    define FAST_EXP2(x) exp2f(x)
#  endif
#else
#  define FAST_EXP2(x) exp2f(x)
#endif

__device__ __forceinline__ short f2bf(float x) {
  __hip_bfloat16 h = __float2bfloat16(x);
  return *(short*)&h;
}

__device__ __forceinline__ bf16x8 cvt8(float4 lo, float4 hi) {
  bf16x8 r;
  r[0] = f2bf(lo.x); r[1] = f2bf(lo.y); r[2] = f2bf(lo.z); r[3] = f2bf(lo.w);
  r[4] = f2bf(hi.x); r[5] = f2bf(hi.y); r[6] = f2bf(hi.z); r[7] = f2bf(hi.w);
  return r;
}

// async 16B global->LDS copy: lds dest = wave-uniform base + lane*16.
__device__ __forceinline__ void dma16(const void* g, void* l) {
  __builtin_amdgcn_global_load_lds(
      (const __attribute__((address_space(1))) unsigned int*)g,
      (__attribute__((address_space(3))) unsigned int*)l, 16, 0, 0);
}

// ---------------------------------------------------------------------------
// Weight prep (all 3 heads): W1 (512x256)->w1t (256x512), W2 (256x128)->
// w2t (128x256), fp32 -> bf16, transposed so k is contiguous. grid (640, 3).
// ---------------------------------------------------------------------------
__global__ __launch_bounds__(256) void prep_w_kernel(
    const float* __restrict__ W1_0, const float* __restrict__ W1_1,
    const float* __restrict__ W1_2,
    const float* __restrict__ W2_0, const float* __restrict__ W2_1,
    const float* __restrict__ W2_2,
    ushort_t* __restrict__ w1t3, ushort_t* __restrict__ w2t3)
{
  const int z = blockIdx.y;
  const float* W1 = z == 0 ? W1_0 : (z == 1 ? W1_1 : W1_2);
  const float* W2 = z == 0 ? W2_0 : (z == 1 ? W2_1 : W2_2);
  int idx = blockIdx.x * 256 + threadIdx.x;
  if (idx < DHID * DIN) {
    int n = idx >> 9, k = idx & (DIN - 1);
    w1t3[(size_t)z * DHID * DIN + idx] = f2bf(W1[(size_t)k * DHID + n]);
  } else {
    int j = idx - DHID * DIN;
    int n = j >> 8, k = j & (DHID - 1);
    w2t3[(size_t)z * DOUT * DHID + j] = f2bf(W2[(size_t)k * DOUT + n]);
  }
}

// ---------------------------------------------------------------------------
// Fused MLP v8 (all heads): y = (relu(x@W1+b1))@W2 + b2, fp32 + col stats.
// Block = 32 rows. Phase 1 = DMA-staged K-loop (16 chunks of BK=32):
//   per chunk, global_load_lds stages W1-tile (16 KB, [j:16cols][q][col]x16B)
//   and fp32 x-tile (4 KB, seg-swizzled (s+row8)&7 to spread banks) into a
//   20 KB double buffer. Wave w computes cols w*64..+64, all 32 rows
//   (2 a-frags cvt'd from fp32 LDS, 4 b-frags, 8 MFMA per chunk).
// Phase 2: W2 b-frags (16 x 16B) bulk-prefetched into regs right after the
//   K-loop (latency hidden by epilogue+barrier); h-tile in padded LDS
//   (stride 264 -> conflict-free b128 A-frags); 32 MFMA per wave.
// hs (16.9 KB) overlays buf0 (safe: buf0's last read is chunk 14, all waves
// past it via the chunk-14 barrier; chunk 15 uses buf1 only).
// grid (256, 3) = 768 blocks = 3/CU exact.
// ---------------------------------------------------------------------------
#define MLP_BUF 20480  // ws 16 KB + xs 4 KB per buffer
__global__ __launch_bounds__(256, 3) void mlp_kernel(
    const float* __restrict__ x0, const float* __restrict__ x1,
    const float* __restrict__ x2,
    const ushort_t* __restrict__ w1t3,
    const float* __restrict__ b1_0, const float* __restrict__ b1_1,
    const float* __restrict__ b1_2,
    const ushort_t* __restrict__ w2t3,
    const float* __restrict__ b2_0, const float* __restrict__ b2_1,
    const float* __restrict__ b2_2,
    float* __restrict__ y3,
    float* __restrict__ colsum, float* __restrict__ colsumsq)
{
  const int z = blockIdx.y;
  const float* X  = z == 0 ? x0 : (z == 1 ? x1 : x2);
  const float* B1 = z == 0 ? b1_0 : (z == 1 ? b1_1 : b1_2);
  const float* B2 = z == 0 ? b2_0 : (z == 1 ? b2_1 : b2_2);
  const ushort_t* W1t = w1t3 + (size_t)z * DHID * DIN;
  const ushort_t* W2t = w2t3 + (size_t)z * DOUT * DHID;
  float* Y    = y3 + (size_t)z * NROWS * DOUT;
  float* csum = colsum + z * DOUT;
  float* csq  = colsumsq + z * DOUT;

  __shared__ __align__(16) char lds[2 * MLP_BUF];
  ushort_t* hs = (ushort_t*)lds;  // [32][264] overlays buf0

  const int tid = threadIdx.x, lane = tid & 63, wave = tid >> 6;
  const int quad = lane >> 4, l16 = lane & 15;
  const int m0 = blockIdx.x * 32;

  // ---- DMA source pointers (chunk 0 base) --------------------------------
  // ws inst j = wave*4+jj covers cols 16j..16j+15: lane i -> col16=i&15,
  // q=i>>4; src byte = col*1024 + q*16 (+ c*64/chunk);
  // LDS layout: j*1024 + q*256 + col16*16.
  const char* w1b = (const char*)W1t;
  const char* wsrc[4];
#pragma unroll
  for (int jj = 0; jj < 4; jj++)
    wsrc[jj] = w1b + (size_t)(16 * (wave * 4 + jj) + l16) * 1024 +
               (lane >> 4) * 16;
  // xs inst j = wave covers rows 8j..8j+7 (fp32): lane i -> row8=i>>3,
  // slot s=i&7 holds global seg g=(s+row8)&7 (bank swizzle);
  // src byte = row*2048 + c*128 + g*16; LDS layout: r*128 + s*16.
  const int row8 = lane >> 3, slot = lane & 7;
  const int gseg = (slot + row8) & 7;
  const char* xsrc = (const char*)X +
      (size_t)(m0 + 8 * wave + row8) * 2048 + gseg * 16;

  // ---- phase 1: K-loop, 16 chunks of BK=32 -------------------------------
  f32x4 acc1[2][4] = {};  // [mt][ct]
  // prime chunk 0 -> buf 0
#pragma unroll
  for (int jj = 0; jj < 4; jj++)
    dma16(wsrc[jj], lds + (wave * 4 + jj) * 1024);
  dma16(xsrc, lds + 16384 + wave * 1024);
  __syncthreads();

  for (int c = 0; c < 16; c++) {
    const int buf = c & 1;
    if (c + 1 < 16) {
      char* dst = lds + (buf ^ 1) * MLP_BUF;
#pragma unroll
      for (int jj = 0; jj < 4; jj++)
        dma16(wsrc[jj] + (c + 1) * 64, dst + (wave * 4 + jj) * 1024);
      dma16(xsrc + (c + 1) * 128, dst + 16384 + wave * 1024);
    }
    const char* wb = lds + buf * MLP_BUF;
    const char* xb = wb + 16384;
    // a-frags: rows mt*16+l16, fp32 segs (2q, 2q+1), swizzled slots
    bf16x8 a[2];
#pragma unroll
    for (int mt = 0; mt < 2; mt++) {
      const int r = mt * 16 + l16, r7 = r & 7;
      const int s0 = (2 * quad - r7) & 7, s1 = (2 * quad + 1 - r7) & 7;
      float4 v0 = *(const float4*)(xb + r * 128 + s0 * 16);
      float4 v1 = *(const float4*)(xb + r * 128 + s1 * 16);
      a[mt] = cvt8(v0, v1);
    }
    bf16x8 b[4];
#pragma unroll
    for (int ct = 0; ct < 4; ct++)
      b[ct] = *(const bf16x8*)(wb + (wave * 4 + ct) * 1024 + quad * 256 +
                               l16 * 16);
#pragma unroll
    for (int mt = 0; mt < 2; mt++)
#pragma unroll
      for (int ct = 0; ct < 4; ct++)
        acc1[mt][ct] = __builtin_amdgcn_mfma_f32_16x16x32_bf16(
            a[mt], b[ct], acc1[mt][ct], 0, 0, 0);
    __syncthreads();
  }

  // ---- bulk-prefetch phase-2 W2 b-frags (fly during epilogue+barrier) ----
  bf16x8 b2f[2][8];  // [ct][kk]: out-cols wave*32+ct*16+l16, k=kk*32+quad*8
#pragma unroll
  for (int ct = 0; ct < 2; ct++)
#pragma unroll
    for (int kk = 0; kk < 8; kk++)
      b2f[ct][kk] = *(const bf16x8*)(W2t +
          (size_t)(wave * 32 + ct * 16 + l16) * DHID + kk * 32 + quad * 8);

  // ---- phase-1 epilogue: bias+relu -> hs (stride 264: conflict-free) -----
#pragma unroll
  for (int ct = 0; ct < 4; ct++) {
    float bb = B1[wave * 64 + ct * 16 + l16];
#pragma unroll
    for (int mt = 0; mt < 2; mt++)
#pragma unroll
      for (int reg = 0; reg < 4; reg++) {
        float v = fmaxf(acc1[mt][ct][reg] + bb, 0.0f);
        hs[(mt * 16 + quad * 4 + reg) * 264 + wave * 64 + ct * 16 + l16] =
            (ushort_t)f2bf(v);
      }
  }
  __syncthreads();

  // ---- phase 2: y = h @ W2 + b2 ------------------------------------------
  f32x4 acc2[2][2] = {};
#pragma unroll
  for (int kk = 0; kk < 8; kk++) {
    bf16x8 a2[2];
#pragma unroll
    for (int mt = 0; mt < 2; mt++)
      a2[mt] = *(const bf16x8*)(hs + (mt * 16 + l16) * 264 + kk * 32 +
                                quad * 8);
#pragma unroll
    for (int mt = 0; mt < 2; mt++)
#pragma unroll
      for (int ct = 0; ct < 2; ct++)
        acc2[mt][ct] = __builtin_amdgcn_mfma_f32_16x16x32_bf16(
            a2[mt], b2f[ct][kk], acc2[mt][ct], 0, 0, 0);
  }

  // ---- phase-2 epilogue: bias, store y, col stats ------------------------
#pragma unroll
  for (int ct = 0; ct < 2; ct++) {
    const int colo = wave * 32 + ct * 16 + l16;
    float bb = B2[colo];
    float cs = 0.0f, cq = 0.0f;
#pragma unroll
    for (int mt = 0; mt < 2; mt++)
#pragma unroll
      for (int reg = 0; reg < 4; reg++) {
        float v = acc2[mt][ct][reg] + bb;
        Y[(size_t)(m0 + mt * 16 + quad * 4 + reg) * DOUT + colo] = v;
        cs += v; cq += v * v;
      }
    cs += __shfl_xor(cs, 16, 64); cs += __shfl_xor(cs, 32, 64);
    cq += __shfl_xor(cq, 16, 64); cq += __shfl_xor(cq, 32, 64);
    if (lane < 16) {
      atomicAdd(&csum[colo], cs);
      atomicAdd(&csq[colo], cq);
    }
  }
}

// ---------------------------------------------------------------------------
// Whitening stats finalize.
// ---------------------------------------------------------------------------
__global__ void stats_kernel(const float* __restrict__ colsum,
                             const float* __restrict__ colsumsq,
                             float* __restrict__ meanv, float* __restrict__ invsd)
{
  int i = threadIdx.x;
  if (i < 3 * DOUT) {
    float mu  = colsum[i] / (float)NROWS;
    float var = (colsumsq[i] - (float)NROWS * mu * mu) / (float)(NROWS - 1);
    float sd  = sqrtf(fmaxf(var, 0.0f)) + 1e-5f;
    meanv[i] = mu;
    invsd[i] = 1.0f / sd;
  }
}

// ---------------------------------------------------------------------------
// Whiten + L2-normalize + pos dots (fp32) + bf16 z (plain V + log2e-scaled U).
// ---------------------------------------------------------------------------
__global__ __launch_bounds__(128) void whiten_kernel(
    const float* __restrict__ y3,
    const float* __restrict__ meanv, const float* __restrict__ invsd,
    ushort_t* __restrict__ zB, ushort_t* __restrict__ zE,
    ushort_t* __restrict__ zF,
    ushort_t* __restrict__ zBs, ushort_t* __restrict__ zEs,
    float* __restrict__ pos)
{
  int row = blockIdx.x, t = threadIdx.x;
  size_t off = (size_t)row * DOUT + t;
  const size_t hs = (size_t)NROWS * DOUT;
  float vB = (y3[off]          - meanv[t])            * invsd[t];
  float vE = (y3[off + hs]     - meanv[DOUT + t])     * invsd[DOUT + t];
  float vF = (y3[off + 2 * hs] - meanv[2 * DOUT + t]) * invsd[2 * DOUT + t];

  __shared__ float red[6], red2[6];
  float nB = vB * vB, nE = vE * vE, nF = vF * vF;
#pragma unroll
  for (int o = 32; o > 0; o >>= 1) {
    nB += __shfl_down(nB, o, 64);
    nE += __shfl_down(nE, o, 64);
    nF += __shfl_down(nF, o, 64);
  }
  int lane = t & 63, wv = t >> 6;
  if (lane == 0) { red[wv * 3] = nB; red[wv * 3 + 1] = nE; red[wv * 3 + 2] = nF; }
  __syncthreads();
  float iB = 1.0f / fmaxf(sqrtf(red[0] + red[3]), 1e-12f);
  float iE = 1.0f / fmaxf(sqrtf(red[1] + red[4]), 1e-12f);
  float iF = 1.0f / fmaxf(sqrtf(red[2] + red[5]), 1e-12f);
  float zb = vB * iB, ze = vE * iE, zf = vF * iF;

  zB[off]  = (ushort_t)f2bf(zb);
  zE[off]  = (ushort_t)f2bf(ze);
  zF[off]  = (ushort_t)f2bf(zf);
  zBs[off] = (ushort_t)f2bf(zb * LOG2E);
  zEs[off] = (ushort_t)f2bf(ze * LOG2E);

  float pBE = zb * ze, pBF = zb * zf, pEF = ze * zf;
#pragma unroll
  for (int o = 32; o > 0; o >>= 1) {
    pBE += __shfl_down(pBE, o, 64);
    pBF += __shfl_down(pBF, o, 64);
    pEF += __shfl_down(pEF, o, 64);
  }
  if (lane == 0) { red2[wv * 3] = pBE; red2[wv * 3 + 1] = pBF; red2[wv * 3 + 2] = pEF; }
  __syncthreads();
  if (t == 0) {
    pos[row]             = red2[0] + red2[3];
    pos[NROWS + row]     = red2[1] + red2[4];
    pos[2 * NROWS + row] = red2[2] + red2[5];
  }
}

// ---------------------------------------------------------------------------
// Gram v7: rowsum_i += sum_j exp2(Us_i . V_j), 5 combos. Async LDS staging,
// G_NCH=32 chunks, grid (32, 8, 5) = 1280 blocks = exactly 5/CU residency.
// ---------------------------------------------------------------------------
#define G_CH  32                    // cols per chunk
#define G_NCH 32                    // chunks per block (1024 cols)
__global__ __launch_bounds__(256, 3) void gram_kernel(
    const ushort_t* __restrict__ zB, const ushort_t* __restrict__ zE,
    const ushort_t* __restrict__ zF,
    const ushort_t* __restrict__ zBs, const ushort_t* __restrict__ zEs,
    float* __restrict__ rowsum)
{
  const ushort_t *U, *V;
  float* rs;
  switch (blockIdx.z) {
    case 0:  U = zBs; V = zB; rs = rowsum;             break;
    case 1:  U = zEs; V = zE; rs = rowsum + NROWS;     break;
    case 2:  U = zBs; V = zE; rs = rowsum + 2 * NROWS; break;
    case 3:  U = zBs; V = zF; rs = rowsum + 3 * NROWS; break;
    default: U = zEs; V = zF; rs = rowsum + 4 * NROWS; break;
  }

  const int tid = threadIdx.x, lane = tid & 63, wave = tid >> 6;
  const int quad = lane >> 4, l16 = lane & 15;
  const int m0 = blockIdx.x * 256 + wave * 64;      // waves stacked in m
  const int col0 = blockIdx.y * (G_CH * G_NCH);

  __shared__ __align__(16) ushort_t sbuf[2][4096];  // 2 x 8 KB

  // cache this wave's A fragments: 64 rows x 128 k (16 frags = 64 VGPR)
  const ushort_t* ua = U + (size_t)(m0 + l16) * DOUT + quad * 8;
  bf16x8 a[4][4];
#pragma unroll
  for (int rt = 0; rt < 4; rt++)
#pragma unroll
    for (int ki = 0; ki < 4; ki++)
      a[rt][ki] = *(const bf16x8*)(ua + rt * 16 * DOUT + ki * 32);

  const char* Vb = (const char*)V;
  const int r_ = lane & 31, hi_ = lane >> 5;
  const int s0 = 4 * wave + hi_, s1 = 4 * wave + 2 + hi_;
  const char* g0 = Vb + (size_t)(col0 + r_) * 256 + (s0 >> 2) * 64 + (s0 & 3) * 16;
  const char* g1 = Vb + (size_t)(col0 + r_) * 256 + (s1 >> 2) * 64 + (s1 & 3) * 16;

  float rsum[4][4] = {};
  const f32x4 zero = {0.0f, 0.0f, 0.0f, 0.0f};

  // prime chunk 0
  dma16(g0, &sbuf[0][(2 * wave) * 512]);
  dma16(g1, &sbuf[0][(2 * wave + 1) * 512]);
  __syncthreads();

  for (int c = 0; c < G_NCH; c++) {
    const int buf = c & 1;
    if (c + 1 < G_NCH) {
      const size_t go = (size_t)(c + 1) * 8192;
      dma16(g0 + go, &sbuf[buf ^ 1][(2 * wave) * 512]);
      dma16(g1 + go, &sbuf[buf ^ 1][(2 * wave + 1) * 512]);
    }
    const char* sb = (const char*)&sbuf[buf][0];
    bf16x8 b[4][2];
#pragma unroll
    for (int ki = 0; ki < 4; ki++)
#pragma unroll
      for (int ct = 0; ct < 2; ct++)
        b[ki][ct] = *(const bf16x8*)(sb + (ki * 4 + quad) * 512 +
                                     (ct * 16 + l16) * 16);
    f32x4 acc[4][2];
#pragma unroll
    for (int ki = 0; ki < 4; ki++)
#pragma unroll
      for (int rt = 0; rt < 4; rt++)
#pragma unroll
        for (int ct = 0; ct < 2; ct++)
          acc[rt][ct] = __builtin_amdgcn_mfma_f32_16x16x32_bf16(
              a[rt][ki], b[ki][ct], ki == 0 ? zero : acc[rt][ct], 0, 0, 0);
#pragma unroll
    for (int rt = 0; rt < 4; rt++)
#pragma unroll
      for (int reg = 0; reg < 4; reg++)
        rsum[rt][reg] += FAST_EXP2(acc[rt][0][reg]) + FAST_EXP2(acc[rt][1][reg]);
    __syncthreads();
  }

#pragma unroll
  for (int rt = 0; rt < 4; rt++)
#pragma unroll
    for (int reg = 0; reg < 4; reg++) {
      float s = rsum[rt][reg];
      s += __shfl_xor(s, 1, 64);
      s += __shfl_xor(s, 2, 64);
      s += __shfl_xor(s, 4, 64);
      s += __shfl_xor(s, 8, 64);
      if (l16 == 0)
        atomicAdd(&rs[m0 + rt * 16 + quad * 4 + reg], s);
    }
}

// ---------------------------------------------------------------------------
// Final loss. logits[i,i] masked to 0: self + (1 - e).
// ---------------------------------------------------------------------------
__global__ __launch_bounds__(1024) void loss_kernel(
    const float* __restrict__ rowsum, const float* __restrict__ pos,
    float* __restrict__ out)
{
  const float* sB  = rowsum;
  const float* sE  = rowsum + NROWS;
  const float* cBE = rowsum + 2 * NROWS;
  const float* cBF = rowsum + 3 * NROWS;
  const float* cEF = rowsum + 4 * NROWS;
  const float* pBE = pos;
  const float* pBF = pos + NROWS;
  const float* pEF = pos + 2 * NROWS;

  const float corr = 1.0f - expf(1.0f);
  float local = 0.0f;
  for (int i = threadIdx.x; i < NROWS; i += 1024) {
    float selB = sB[i] + corr;
    float selE = sE[i] + corr;
    local += __logf(selB + cBE[i]) - pBE[i];
    local += __logf(selB + cBF[i]) - pBF[i];
    local += __logf(selE + cEF[i]) - pEF[i];
  }
  __shared__ float red[16];
#pragma unroll
  for (int o = 32; o > 0; o >>= 1) local += __shfl_down(local, o, 64);
  int lane = threadIdx.x & 63, wv = threadIdx.x >> 6;
  if (lane == 0) red[wv] = local;
  __syncthreads();
  if (threadIdx.x == 0) {
    float t = 0.0f;
#pragma unroll
    for (int w = 0; w < 16; w++) t += red[w];
    out[0] = t / (3.0f * (float)NROWS);
  }
}

// ---------------------------------------------------------------------------
extern "C" void kernel_launch(void* const* d_in, const int* in_sizes, int n_in,
                              void* d_out, int out_size, void* d_ws, size_t ws_size,
                              hipStream_t stream)
{
  const float* xs[3] = {(const float*)d_in[0], (const float*)d_in[1], (const float*)d_in[2]};
  const float* W1[3] = {(const float*)d_in[3], (const float*)d_in[7],  (const float*)d_in[11]};
  const float* b1[3] = {(const float*)d_in[4], (const float*)d_in[8],  (const float*)d_in[12]};
  const float* W2[3] = {(const float*)d_in[5], (const float*)d_in[9],  (const float*)d_in[13]};
  const float* b2[3] = {(const float*)d_in[6], (const float*)d_in[10], (const float*)d_in[14]};

  float* ws = (float*)d_ws;
  // workspace layout (float offsets):
  float* colsum   = ws;            // 384   [zeroed]
  float* colsumsq = ws + 384;      // 384   [zeroed]
  float* rowsum   = ws + 768;      // 5*8192 [zeroed]
  float* meanv    = ws + 41728;    // 384
  float* invsd    = ws + 42112;    // 384
  float* pos      = ws + 42496;    // 3*8192 -> ends 67072
  ushort_t* w1t3 = (ushort_t*)(ws + 67072);    // 3*256*512 bf16 = 196608 fl
  ushort_t* w2t3 = (ushort_t*)(ws + 263680);   // 3*128*256 bf16 = 49152 fl
  float*    y3   = ws + 312832;                // 3*8192*128 fp32 = 3145728 fl
  ushort_t* zB   = (ushort_t*)(ws + 3458560);  // 5 x 8192*128 bf16
  ushort_t* zE   = zB  + (size_t)NROWS * DOUT;
  ushort_t* zF   = zE  + (size_t)NROWS * DOUT;
  ushort_t* zBs  = zF  + (size_t)NROWS * DOUT;
  ushort_t* zEs  = zBs + (size_t)NROWS * DOUT;
  // peak ws usage: 6,080,000 floats = 24.3 MB

  hipMemsetAsync(ws, 0, 41728 * sizeof(float), stream);

  prep_w_kernel<<<dim3(640, 3), 256, 0, stream>>>(
      W1[0], W1[1], W1[2], W2[0], W2[1], W2[2], w1t3, w2t3);
  mlp_kernel<<<dim3(256, 3), 256, 0, stream>>>(
      xs[0], xs[1], xs[2], w1t3, b1[0], b1[1], b1[2],
      w2t3, b2[0], b2[1], b2[2], y3, colsum, colsumsq);
  stats_kernel<<<1, 3 * DOUT, 0, stream>>>(colsum, colsumsq, meanv, invsd);
  whiten_kernel<<<NROWS, 128, 0, stream>>>(
      y3, meanv, invsd, zB, zE, zF, zBs, zEs, pos);
  gram_kernel<<<dim3(32, 8, 5), 256, 0, stream>>>(zB, zE, zF, zBs, zEs, rowsum);
  loss_kernel<<<1, 1024, 0, stream>>>(rowsum, pos, (float*)d_out);
}